// Round 7
// baseline (23379.181 us; speedup 1.0000x reference)
//
#include <hip/hip_runtime.h>
#include <hip/hip_bf16.h>
#include <cmath>

#define NEG_ (-1000000000.0f)

// dims
#define V_ 30000
#define E_ 300
#define H_ 512
#define B_ 64
#define LQ_ 64
#define A_ 7
#define LO_ 16
#define S_ 50
#define LS_ 32
#define W_ 3

__device__ __forceinline__ float wred_sum(float v){
#pragma unroll
  for (int o=32;o>0;o>>=1) v += __shfl_xor(v,o);
  return v;
}
__device__ __forceinline__ float wred_max(float v){
#pragma unroll
  for (int o=32;o>0;o>>=1) v = fmaxf(v,__shfl_xor(v,o));
  return v;
}
__device__ __forceinline__ float sigf(float x){ return 1.f/(1.f+expf(-x)); }
__device__ __forceinline__ float entf(float p){ return -(p*log2f(p) + (1.f-p)*log2f(1.f-p)); }

// ---------------- small kernels ----------------
__global__ void fill_from_k(float* p, const float* v, long n){
  long i = (long)blockIdx.x*256 + threadIdx.x; if (i<n) p[i]=v[0];
}
__global__ void score_fold_k(const float* __restrict__ w1, const float* __restrict__ b1,
                             const float* __restrict__ w2, const float* __restrict__ b2,
                             float* scv, float* scc){
  int k = blockIdx.x*256+threadIdx.x;
  if (k < H_){ float s=0; for(int j=0;j<H_;j++) s += w1[(long)k*H_+j]*w2[j]; scv[k]=s; }
  if (blockIdx.x==0 && threadIdx.x==0){ float s=0; for(int j=0;j<H_;j++) s += b1[j]*w2[j]; *scc = s + b2[0]; }
}

// ---------------- tiled f32 GEMM ----------------
// out[r,g] = bias[g] + sum_k A_row(r)[k] * W(g,k)
// WKG=false: W is [G][K] row-major (gate-major, GRU weights)
// WKG=true : W is [K][G] row-major (natural x@W layout)
// A row address: gather ? A + gather[r*gstep]*lda : A + r*lda.  A==null -> product 0.
template<bool WKG>
__global__ __launch_bounds__(256) void gemm_k(
    const float* __restrict__ A, long lda,
    const float* __restrict__ Wm, const float* __restrict__ bias,
    float* __restrict__ out, int ldo,
    int R, int G, int Kd, int relu,
    const int* __restrict__ gather, int gstep)
{
  __shared__ float As[64][17];
  __shared__ float WsF[64*17];   // GK: [row][kk] at row*17+kk ; KG: [kk][gg] at kk*65+gg
  int tid = threadIdx.x;
  int tx = tid & 15, ty = tid >> 4;
  int r0 = blockIdx.x * 64, g0 = blockIdx.y * 64;
  float acc[4][4] = {};
  if (A != nullptr){
    int row = tid >> 2;
    int kk0 = (tid & 3) * 4;
    const float* ap = nullptr;
    int rr = r0 + row;
    if (rr < R){
      long arow = gather ? (long)gather[(long)rr*gstep] : (long)rr;
      ap = A + arow*lda;
    }
    const float* wp = (!WKG && (g0+row < G)) ? (Wm + (long)(g0+row)*Kd) : nullptr;
    int kkw = tid >> 4, gg0 = (tid & 15) * 4;
    for (int k0 = 0; k0 < Kd; k0 += 16){
#pragma unroll
      for (int q=0;q<4;q++){
        int kk = kk0+q;
        float va = 0.f;
        if (ap && k0+kk < Kd) va = ap[k0+kk];
        As[row][kk] = va;
      }
      if (WKG){
#pragma unroll
        for (int q=0;q<4;q++){
          int gg = gg0+q;
          float vw = 0.f;
          if (k0+kkw < Kd && g0+gg < G) vw = Wm[(long)(k0+kkw)*G + g0+gg];
          WsF[kkw*65+gg] = vw;
        }
      } else {
#pragma unroll
        for (int q=0;q<4;q++){
          int kk = kk0+q;
          float vw = 0.f;
          if (wp && k0+kk < Kd) vw = wp[k0+kk];
          WsF[row*17+kk] = vw;
        }
      }
      __syncthreads();
#pragma unroll
      for (int kk=0; kk<16; kk++){
        float a[4], b[4];
#pragma unroll
        for(int i=0;i<4;i++) a[i] = As[ty*4+i][kk];
#pragma unroll
        for(int j=0;j<4;j++) b[j] = WKG ? WsF[kk*65 + tx*4+j] : WsF[(tx*4+j)*17 + kk];
#pragma unroll
        for(int i=0;i<4;i++)
#pragma unroll
          for(int j=0;j<4;j++) acc[i][j] += a[i]*b[j];
      }
      __syncthreads();
    }
  }
#pragma unroll
  for (int i=0;i<4;i++){
    int r = r0 + ty*4 + i;
    if (r >= R) continue;
#pragma unroll
    for (int j=0;j<4;j++){
      int g = g0 + tx*4 + j;
      if (g >= G) continue;
      float vv = acc[i][j] + (bias ? bias[g] : 0.f);
      if (relu) vv = fmaxf(vv, 0.f);
      out[(long)r*ldo + g] = vv;
    }
  }
}

// ---------------- GRU gate fusion ----------------
__global__ void gru_gate_k(const float* __restrict__ xg, const float* __restrict__ gh,
                           float* __restrict__ seq, int t, int N, int T){
  long idx = (long)blockIdx.x*256 + threadIdx.x;
  if (idx >= (long)N*H_) return;
  int n = (int)(idx >> 9); int j = (int)(idx & 511);
  long o = (long)n*1536;
  float xr = xg[o+j], xz = xg[o+512+j], xn = xg[o+1024+j];
  float hr = gh[o+j], hz = gh[o+512+j], hn = gh[o+1024+j];
  float r = sigf(xr+hr);
  float z = sigf(xz+hz);
  float nn = tanhf(xn + r*hn);
  float hp = (t==0) ? 0.f : seq[((long)n*T + (t-1))*H_ + j];
  seq[((long)n*T + t)*H_ + j] = (1.f - z)*nn + z*hp;
}

// ---------------- attflat score: s[r] += sum_g relu(X@w1 + b1)[r,g]*w2[g] ----------------
// w1 in natural [K=512][G=512] layout
__global__ __launch_bounds__(256) void flatscore_k(
    const float* __restrict__ A, const float* __restrict__ w1,
    const float* __restrict__ b1, const float* __restrict__ w2,
    float* __restrict__ sOut, int R)
{
  __shared__ float As[64][17];
  __shared__ float Ws2[16][65];
  int tid=threadIdx.x; int tx=tid&15, ty=tid>>4;
  int r0=blockIdx.x*64, g0=blockIdx.y*64;
  float acc[4][4]={};
  int row=tid>>2, kk0=(tid&3)*4;
  int kkw=tid>>4, gg0=(tid&15)*4;
  for (int k0=0;k0<512;k0+=16){
#pragma unroll
    for(int q=0;q<4;q++){
      int kk=kk0+q;
      As[row][kk] = (r0+row<R)? A[(long)(r0+row)*512 + k0+kk] : 0.f;
    }
#pragma unroll
    for(int q=0;q<4;q++){
      int gg=gg0+q;
      Ws2[kkw][gg] = w1[(long)(k0+kkw)*512 + g0+gg];
    }
    __syncthreads();
#pragma unroll
    for(int kk=0;kk<16;kk++){
      float a[4],b[4];
#pragma unroll
      for(int i=0;i<4;i++) a[i]=As[ty*4+i][kk];
#pragma unroll
      for(int j=0;j<4;j++) b[j]=Ws2[kk][tx*4+j];
#pragma unroll
      for(int i=0;i<4;i++)
#pragma unroll
        for(int j=0;j<4;j++) acc[i][j]+=a[i]*b[j];
    }
    __syncthreads();
  }
  float pr[4];
#pragma unroll
  for(int i=0;i<4;i++){
    float ssum=0;
#pragma unroll
    for(int j=0;j<4;j++){
      int g=g0+tx*4+j;
      float y=fmaxf(acc[i][j]+b1[g],0.f);
      ssum += y*w2[g];
    }
    pr[i]=ssum;
  }
  __syncthreads();
#pragma unroll
  for(int i=0;i<4;i++) As[ty*4+i][tx]=pr[i];
  __syncthreads();
  if (tid<64){
    float ssum=0;
#pragma unroll
    for(int x=0;x<16;x++) ssum+=As[tid][x];
    if (r0+tid < R) atomicAdd(&sOut[r0+tid], ssum);
  }
}

// ---------------- attflat softmax + weighted sum ----------------
__global__ void flat_soft_k(const float* __restrict__ s, const int* __restrict__ ix,
                            const float* __restrict__ X, float* __restrict__ outp, int T){
  int n = blockIdx.x;
  int tid = threadIdx.x;
  __shared__ float aw[64];
  if (tid < 64){
    float val = -INFINITY;
    if (tid < T) val = (ix[(long)n*T+tid]==0) ? NEG_ : s[(long)n*T+tid];
    float mx = wred_max(val);
    float e = (tid < T) ? expf(val - mx) : 0.f;
    float ssum = wred_sum(e);
    if (tid < T) aw[tid] = e/ssum;
  }
  __syncthreads();
  for (int h = tid; h < 512; h += 256){
    float acc = 0;
    for (int t=0;t<T;t++) acc += aw[t]*X[((long)n*T+t)*512 + h];
    outp[(long)n*512+h] = acc;
  }
}

// ---------------- span scores (span_p computed on the fly from cp_feat) ----------------
__global__ void sent_empty_k(const int* __restrict__ cp_ix, int* __restrict__ se){
  int i = blockIdx.x*256+threadIdx.x;
  if (i < B_*S_){ const int* p = cp_ix + (long)i*LS_; int e=1; for(int t=0;t<LS_;t++) if(p[t]!=0){e=0;break;} se[i]=e; }
}
__global__ void qdot_k(const float* __restrict__ que_vec, const float* __restrict__ scv, float* qdot){
  int b = blockIdx.x; int d = threadIdx.x;  // 128 threads
  const float* qv = que_vec + (long)b*512;
  float m = 0.25f*(qv[4*d]+qv[4*d+1]+qv[4*d+2]+qv[4*d+3]);
  float v = m*scv[d];
  __shared__ float sred[2];
  float w = wred_sum(v);
  if ((threadIdx.x&63)==0) sred[threadIdx.x>>6] = w;
  __syncthreads();
  if (threadIdx.x==0) qdot[b] = sred[0]+sred[1];
}
__global__ void que_ent_k(const float* __restrict__ que_vec, const float* __restrict__ scv,
                          const float* __restrict__ scc, float* que_ent){
  int b = blockIdx.x; int lane = threadIdx.x;  // 64
  float acc=0; for(int d=lane;d<512;d+=64) acc += que_vec[(long)b*512+d]*scv[d];
  acc = wred_sum(acc);
  if (lane==0){ float p = sigf(acc + scc[0]); que_ent[b] = entf(p); }
}
__global__ void ce_k(const float* __restrict__ cp_feat,
                     const float* __restrict__ qdot, const float* __restrict__ scv,
                     const float* __restrict__ scc, float* __restrict__ ce){
  int bj = blockIdx.x;  // 64*150
  int b = bj/150, j = bj%150;
  int sI = j/3, wi = j%3;
  int lane = threadIdx.x;  // 64
  // dsp = span_p[bj] . scv = (1/3) * sum_e span[e]*scv[e/3]
  float dsp = 0.f;
  for (int e=lane; e<1536; e+=64){
    int off = e >> 9; int dd = e & 511;
    if (off <= wi && sI+off < S_)
      dsp += cp_feat[((long)(b*S_ + sI+off))*512 + dd] * scv[e/3];
  }
  // dqe: qe[d] for d in [128,512): mean of 4 consecutive span elements (same off)
  float dqe = 0.f;
  for (int d=128+lane; d<512; d+=64){
    int e0 = 4*d - 512;
    int off = e0 >> 9; int dd = e0 & 511;
    float m = 0.f;
    if (off <= wi && sI+off < S_){
      const float* cf = cp_feat + ((long)(b*S_ + sI+off))*512 + dd;
      m = 0.25f*(cf[0]+cf[1]+cf[2]+cf[3]);
    }
    dqe += m*scv[d];
  }
  dsp = wred_sum(dsp)*(1.f/3.f); dqe = wred_sum(dqe);
  if (lane==0){
    float evi = sigf(dsp + scc[0]);
    float pq  = sigf(dqe + qdot[b] + scc[0]);
    ce[bj] = evi * entf(pq);
  }
}
__global__ void argmax_k(const float* __restrict__ ce, const float* __restrict__ que_ent,
                         const int* __restrict__ sent_e, const float* __restrict__ cp_feat,
                         float* __restrict__ evi_feat){
  int b = blockIdx.x;
  __shared__ int bix;
  if (threadIdx.x==0){
    float best = -INFINITY; int bidx = 0;
    for (int j=0;j<150;j++){
      float v = sent_e[b*S_ + j/3] ? NEG_ : (que_ent[b] - ce[b*150+j]);
      if (v > best){ best = v; bidx = j; }
    }
    bix = bidx;
  }
  __syncthreads();
  int sI = bix/3, wi = bix%3;
  for (int d=threadIdx.x; d<512; d+=blockDim.x){
    float sum = 0.f;
#pragma unroll
    for (int q=0;q<3;q++){
      int e = 3*d + q; int off = e >> 9; int dd = e & 511;
      if (off <= wi && sI+off < S_) sum += cp_feat[((long)(b*S_ + sI+off))*512 + dd];
    }
    evi_feat[(long)b*512+d] = sum * (1.f/3.f);
  }
}

// ---------------- bilinear attention ----------------
__global__ void u_k(const float* __restrict__ v_f, const float* __restrict__ hmat, float* __restrict__ u){
  int idx = blockIdx.x*256+threadIdx.x;  // 64*2*512
  if (idx >= 65536) return;
  int k = idx & 511; int g = (idx >> 9) & 1; int b = idx >> 10;
  u[idx] = v_f[(long)b*512+k]*hmat[(long)g*512+k];
}
__global__ void att_k(const float* __restrict__ u, const float* __restrict__ q_,
                      const float* __restrict__ hbias, float* __restrict__ att){
  int bg = blockIdx.x;  // 128
  int b = bg >> 1, g = bg & 1;
  int lane = threadIdx.x;  // 64
  const float* up = u + (long)bg*512;
  const float* qp = q_ + ((long)b*64 + lane)*512;
  float dot = 0;
  for (int k=0;k<512;k++) dot += up[k]*qp[k];
  dot += hbias[g];
  float mx = wred_max(dot);
  float e = expf(dot - mx);
  float ssum = wred_sum(e);
  att[(long)bg*64 + lane] = e/ssum;
}
__global__ void bi_k(const float* __restrict__ att, const float* __restrict__ vg,
                     const float* __restrict__ qg, float* __restrict__ bi, int g){
  int b = blockIdx.x; int k = threadIdx.x;  // 512
  __shared__ float a[64];
  if (k < 64) a[k] = att[((long)b*2+g)*64 + k];
  __syncthreads();
  float acc = 0;
  for (int q=0;q<64;q++) acc += a[q]*qg[((long)b*64+q)*512 + k];
  bi[(long)b*512+k] = vg[(long)b*512+k]*acc;
}
__global__ void addq_k(float* __restrict__ q, const float* __restrict__ upd){
  long idx = (long)blockIdx.x*256 + threadIdx.x;  // 64*64*512
  if (idx >= 64L*64*512) return;
  int h = (int)(idx & 511); int b = (int)(idx >> 15);
  q[idx] += upd[(long)b*512 + h];
}
__global__ void meanq_k(const float* __restrict__ q, float* __restrict__ fq){
  int b = blockIdx.x; int h = threadIdx.x;  // 512
  float acc=0; for(int t=0;t<64;t++) acc += q[((long)b*64+t)*512+h];
  fq[(long)b*512+h] = acc*(1.f/64.f);
}

// ---------------- classifier ----------------
__global__ void fuse_k(const float* __restrict__ que_vec, const float* __restrict__ opt_feat,
                       const float* __restrict__ evi_feat, const float* __restrict__ fuse_qe,
                       float* __restrict__ fuse){
  long idx = (long)blockIdx.x*256+threadIdx.x;  // 448*4096
  if (idx >= 448L*4096) return;
  int e = (int)(idx & 4095); long r = idx >> 12;
  int c = e >> 9, d = e & 511;
  int b = (int)(r / 7);
  float qv = que_vec[(long)b*512+d], ov = opt_feat[r*512+d], ev = evi_feat[(long)b*512+d], fq = fuse_qe[(long)b*512+d];
  float val;
  switch(c){
    case 0: val=qv; break; case 1: val=ov; break; case 2: val=ev; break;
    case 3: val=qv*ev; break; case 4: val=ev*ov; break; case 5: val=qv*ov; break;
    case 6: val=fq; break; default: val=qv*ov*fq; break;
  }
  fuse[idx]=val;
}
__global__ void cls_final_k(const float* __restrict__ clsh, const float* __restrict__ cls_w2,
                            const float* __restrict__ cls_b2, const int* __restrict__ opt_ix,
                            float* __restrict__ outp){
  int r = blockIdx.x;  // 448
  int lane = threadIdx.x;  // 64
  float acc=0;
  for (int j=lane;j<512;j+=64) acc += clsh[(long)r*512+j]*cls_w2[j];
  acc = wred_sum(acc);
  if (lane==0){
    bool empty = true;
    for (int t=0;t<LO_;t++) if (opt_ix[(long)r*LO_+t]!=0) { empty=false; break; }
    outp[r] = empty ? NEG_ : (acc + cls_b2[0]);
  }
}
__global__ void count_k(const int* __restrict__ opt_ix, float* __restrict__ outp){
  int b = threadIdx.x;  // 64
  if (b < B_){
    int c=0;
    for(int a=0;a<A_;a++){
      bool e=true;
      for(int t=0;t<LO_;t++) if(opt_ix[((long)b*A_+a)*LO_+t]!=0){e=false;break;}
      if (!e) c++;
    }
    outp[448+b]=(float)c;
  }
}

// ---------------- host orchestration ----------------
static size_t total_need(long Nc){
  long Nx = Nc > 448 ? Nc : 448;
  long Rm = (Nc*32 > 7168) ? Nc*32 : 7168;
  long Pm = Nc > 448 ? Nc : 448;
  size_t s = 0;
  s += 64L*64*512;        // que_seq
  s += 448L*16*512;       // opt_seq
  s += (size_t)Nc*32*512; // chunk_seq
  s += 2*(size_t)Nx*1536; // xg, gh
  s += 512 + 8;           // scv, scc
  s += (size_t)Rm;        // sbuf
  s += (size_t)Pm*512;    // pre
  s += 3200L*512;         // cp_feat
  s += 448L*512;          // opt_feat
  s += 64L*512;           // que_vec
  s += 64 + 64 + 9600 + 3200; // qdot, que_ent, ce, sent_e
  s += 64L*512;           // evi_feat
  s += 4096L*512;         // q_
  s += 128L*512 + 128L*64;// u, att
  s += 64L*512*2;         // v_f, vg
  s += 4096L*512;         // qg
  s += 64L*512*3;         // bi, upd, fuse_qe
  s += 448L*4096;         // fuse
  s += 448L*512;          // clsh
  return s;
}

extern "C" void kernel_launch(void* const* d_in, const int* in_sizes, int n_in,
                              void* d_out, int out_size, void* d_ws, size_t ws_size,
                              hipStream_t stream) {
  const int*   que_ix  = (const int*)d_in[0];
  const int*   opt_ix  = (const int*)d_in[1];
  const int*   cp_ix   = (const int*)d_in[2];
  const float* emb     = (const float*)d_in[3];
  const float* gru_wi  = (const float*)d_in[4];
  const float* gru_wh  = (const float*)d_in[5];
  const float* gru_bi  = (const float*)d_in[6];
  const float* gru_bh  = (const float*)d_in[7];
  const float* flat_w1 = (const float*)d_in[8];
  const float* flat_b1 = (const float*)d_in[9];
  const float* flat_w2 = (const float*)d_in[10];
  const float* flat_b2 = (const float*)d_in[11];
  const float* flat_mw = (const float*)d_in[12];
  const float* flat_mb = (const float*)d_in[13];
  const float* score_w1= (const float*)d_in[14];
  const float* score_b1= (const float*)d_in[15];
  const float* score_w2= (const float*)d_in[16];
  const float* score_b2= (const float*)d_in[17];
  const float* ba_vw   = (const float*)d_in[18];
  const float* ba_vb   = (const float*)d_in[19];
  const float* ba_qw   = (const float*)d_in[20];
  const float* ba_qb   = (const float*)d_in[21];
  const float* ba_hmat = (const float*)d_in[22];
  const float* ba_hbias= (const float*)d_in[23];
  const float* bc_vw   = (const float*)d_in[24];
  const float* bc_vb   = (const float*)d_in[25];
  const float* bc_qw   = (const float*)d_in[26];
  const float* bc_qb   = (const float*)d_in[27];
  const float* prj_w   = (const float*)d_in[28];
  const float* prj_b   = (const float*)d_in[29];
  const float* cls_w1  = (const float*)d_in[30];
  const float* cls_b1  = (const float*)d_in[31];
  const float* cls_w2  = (const float*)d_in[32];
  const float* cls_b2  = (const float*)d_in[33];

  // pick largest even cp-chunk that fits ws_size
  size_t avail = ws_size / sizeof(float);
  long Nc = 3200;
  while (Nc > 2 && total_need(Nc) > avail) Nc -= 2;

  long Nx = Nc > 448 ? Nc : 448;
  long Rm = (Nc*32 > 7168) ? Nc*32 : 7168;
  long Pm = Nc > 448 ? Nc : 448;

  float* Wp = (float*)d_ws;
  size_t o = 0;
  auto F = [&](size_t n){ float* p = Wp + o; o += n; return p; };
  float* que_seq  = F(64L*64*512);
  float* opt_seq  = F(448L*16*512);
  float* chunk_seq= F((size_t)Nc*32*512);
  float* xg       = F((size_t)Nx*1536);
  float* gh       = F((size_t)Nx*1536);
  float* scv      = F(512);
  float* scc      = F(8);
  float* sbuf     = F((size_t)Rm);
  float* pre      = F((size_t)Pm*512);
  float* cp_feat  = F(3200L*512);
  float* opt_feat = F(448L*512);
  float* que_vec  = F(64L*512);
  float* qdot     = F(64);
  float* que_ent  = F(64);
  float* ce       = F(9600);
  int*   sent_e   = (int*)F(3200);
  float* evi_feat = F(64L*512);
  float* q_       = F(4096L*512);
  float* u        = F(128L*512);
  float* att      = F(128L*64);
  float* v_f      = F(64L*512);
  float* vg       = F(64L*512);
  float* qg       = F(4096L*512);
  float* bi       = F(64L*512);
  float* upd      = F(64L*512);
  float* fuse_qe  = F(64L*512);
  float* fuse     = F(448L*4096);
  float* clsh     = F(448L*512);

  dim3 blk(256);
  hipLaunchKernelGGL(score_fold_k, dim3(2), blk, 0, stream, score_w1, score_b1, score_w2, score_b2, scv, scc);

  // ---- GRU (per-step GEMMs) ----
  auto run_gru = [&](const int* ix, int N, int Tn, float* seq){
    dim3 gA((unsigned)((N+63)/64), 24);
    for (int t=0; t<Tn; t++){
      hipLaunchKernelGGL(gemm_k<false>, gA, blk, 0, stream,
                         emb, (long)E_, gru_wi, gru_bi, xg, 1536, N, 1536, E_, 0, ix + t, Tn);
      const float* hp = (t==0) ? nullptr : (seq + (long)(t-1)*512);
      hipLaunchKernelGGL(gemm_k<false>, gA, blk, 0, stream,
                         hp, (long)Tn*512, gru_wh, gru_bh, gh, 1536, N, 1536, 512, 0, nullptr, 0);
      long tot = (long)N*512;
      hipLaunchKernelGGL(gru_gate_k, dim3((unsigned)((tot+255)/256)), blk, 0, stream, xg, gh, seq, t, N, Tn);
    }
  };
  // ---- attflat ----
  auto run_attflat = [&](const float* seq, const int* ix, int N, int Tn, float* outfeat){
    int R = N*Tn;
    hipLaunchKernelGGL(fill_from_k, dim3((unsigned)((R+255)/256)), blk, 0, stream, sbuf, flat_b2, (long)R);
    hipLaunchKernelGGL(flatscore_k, dim3((unsigned)((R+63)/64), 8), blk, 0, stream, seq, flat_w1, flat_b1, flat_w2, sbuf, R);
    hipLaunchKernelGGL(flat_soft_k, dim3((unsigned)N), blk, 0, stream, sbuf, ix, seq, pre, Tn);
    hipLaunchKernelGGL(gemm_k<true>, dim3((unsigned)((N+63)/64), 8), blk, 0, stream,
                       pre, 512L, flat_mw, flat_mb, outfeat, 512, N, 512, 512, 0, nullptr, 0);
  };

  run_gru(que_ix, 64, 64, que_seq);
  run_attflat(que_seq, que_ix, 64, 64, que_vec);
  run_gru(opt_ix, 448, 16, opt_seq);
  run_attflat(opt_seq, opt_ix, 448, 16, opt_feat);
  // cp branch in chunks
  for (long start = 0; start < 3200; start += Nc){
    long Ncur = (3200 - start < Nc) ? (3200 - start) : Nc;
    run_gru(cp_ix + start*32, (int)Ncur, 32, chunk_seq);
    run_attflat(chunk_seq, cp_ix + start*32, (int)Ncur, 32, cp_feat + start*512);
  }

  // ---- span scores + info gain + evidence ----
  hipLaunchKernelGGL(sent_empty_k, dim3((B_*S_+255)/256), blk, 0, stream, cp_ix, sent_e);
  hipLaunchKernelGGL(qdot_k, dim3(64), dim3(128), 0, stream, que_vec, scv, qdot);
  hipLaunchKernelGGL(que_ent_k, dim3(64), dim3(64), 0, stream, que_vec, scv, scc, que_ent);
  hipLaunchKernelGGL(ce_k, dim3(64*150), dim3(64), 0, stream, cp_feat, qdot, scv, scc, ce);
  hipLaunchKernelGGL(argmax_k, dim3(64), dim3(256), 0, stream, ce, que_ent, sent_e, cp_feat, evi_feat);

  // ---- bilinear attention fusion ----
  hipLaunchKernelGGL(gemm_k<true>, dim3(1, 8), blk, 0, stream,
                     evi_feat, 512L, ba_vw, ba_vb, v_f, 512, 64, 512, 512, 1, nullptr, 0);
  hipLaunchKernelGGL(gemm_k<true>, dim3(64, 8), blk, 0, stream,
                     que_seq, 512L, ba_qw, ba_qb, q_, 512, 4096, 512, 512, 1, nullptr, 0);
  hipLaunchKernelGGL(u_k, dim3(65536/256), blk, 0, stream, v_f, ba_hmat, u);
  hipLaunchKernelGGL(att_k, dim3(128), dim3(64), 0, stream, u, q_, ba_hbias, att);
  for (int g=0; g<2; g++){
    hipLaunchKernelGGL(gemm_k<true>, dim3(64, 8), blk, 0, stream,
                       que_seq, 512L, bc_qw + (long)g*512*512, bc_qb + (long)g*512, qg, 512, 4096, 512, 512, 1, nullptr, 0);
    hipLaunchKernelGGL(gemm_k<true>, dim3(1, 8), blk, 0, stream,
                       evi_feat, 512L, bc_vw + (long)g*512*512, bc_vb + (long)g*512, vg, 512, 64, 512, 512, 1, nullptr, 0);
    hipLaunchKernelGGL(bi_k, dim3(64), dim3(512), 0, stream, att, vg, qg, bi, g);
    hipLaunchKernelGGL(gemm_k<true>, dim3(1, 8), blk, 0, stream,
                       bi, 512L, prj_w + (long)g*512*512, prj_b + (long)g*512, upd, 512, 64, 512, 512, 0, nullptr, 0);
    hipLaunchKernelGGL(addq_k, dim3((unsigned)((64L*64*512+255)/256)), blk, 0, stream, que_seq, upd);
  }
  hipLaunchKernelGGL(meanq_k, dim3(64), dim3(512), 0, stream, que_seq, fuse_qe);

  // ---- classifier ----
  hipLaunchKernelGGL(fuse_k, dim3((unsigned)((448L*4096+255)/256)), blk, 0, stream, que_vec, opt_feat, evi_feat, fuse_qe, fuse);
  hipLaunchKernelGGL(gemm_k<true>, dim3(7, 8), blk, 0, stream,
                     fuse, 4096L, cls_w1, cls_b1, clsh, 512, 448, 512, 4096, 1, nullptr, 0);
  hipLaunchKernelGGL(cls_final_k, dim3(448), dim3(64), 0, stream, clsh, cls_w2, cls_b2, opt_ix, (float*)d_out);
  hipLaunchKernelGGL(count_k, dim3(1), dim3(64), 0, stream, opt_ix, (float*)d_out);
}

// Round 8
// 15386.749 us; speedup vs baseline: 1.5194x; 1.5194x over previous
//
#include <hip/hip_runtime.h>
#include <hip/hip_bf16.h>
#include <cmath>

#define NEG_ (-1000000000.0f)

// dims
#define V_ 30000
#define E_ 300
#define H_ 512
#define B_ 64
#define LQ_ 64
#define A_ 7
#define LO_ 16
#define S_ 50
#define LS_ 32
#define W_ 3

typedef __attribute__((ext_vector_type(8))) short bh8;
typedef __attribute__((ext_vector_type(4))) float f4;

__device__ __forceinline__ float wred_sum(float v){
#pragma unroll
  for (int o=32;o>0;o>>=1) v += __shfl_xor(v,o);
  return v;
}
__device__ __forceinline__ float wred_max(float v){
#pragma unroll
  for (int o=32;o>0;o>>=1) v = fmaxf(v,__shfl_xor(v,o));
  return v;
}
__device__ __forceinline__ float sigf(float x){ return 1.f/(1.f+expf(-x)); }
__device__ __forceinline__ float entf(float p){ return -(p*log2f(p) + (1.f-p)*log2f(1.f-p)); }
__device__ __forceinline__ unsigned short f2b(float f){
  unsigned x = __float_as_uint(f);
  x = x + 0x7FFF + ((x>>16)&1);
  return (unsigned short)(x>>16);
}
__device__ __forceinline__ float b2f(unsigned short u){
  return __uint_as_float(((unsigned)u)<<16);
}

// ---------------- small kernels ----------------
__global__ void score_fold_k(const float* __restrict__ w1, const float* __restrict__ b1,
                             const float* __restrict__ w2, const float* __restrict__ b2,
                             float* scv, float* scc){
  int k = blockIdx.x*256+threadIdx.x;
  if (k < H_){ float s=0; for(int j=0;j<H_;j++) s += w1[(long)k*H_+j]*w2[j]; scv[k]=s; }
  if (blockIdx.x==0 && threadIdx.x==0){ float s=0; for(int j=0;j<H_;j++) s += b1[j]*w2[j]; *scc = s + b2[0]; }
}

// ---------------- bf16 MFMA GEMM ----------------
// out[r,g] = bias[g] + sum_k A_row(r)[k] * W(g,k)   (f32 in, bf16 MFMA, f32 or bf16 out)
// WKG=false: W is [G][K] row-major (GRU weights).  WKG=true: W is [K][G] row-major.
// A row: gather ? A + gather[r*gstep]*lda : A + r*lda.  A==null -> acc 0 (out = bias).
// 64x64 tile, 4 waves (2x2 of 32x32), each wave 2x2 mfma_f32_16x16x32_bf16 frags.
// LDS layout [row][k] bf16, row stride 40 (pad 8) -> frag load = one b128 read:
//   lane l reads (base + (l&15)) row, k-slice (l>>4)*8..+7 (A/B frag: 8 contiguous k per lane).
// C/D: col = lane&15, row = (lane>>4)*4 + reg  [m89-verified].
template<bool WKG, bool OUTB>
__global__ __launch_bounds__(256) void mgemm_k(
    const float* __restrict__ A, long lda,
    const float* __restrict__ Wm, const float* __restrict__ bias,
    void* __restrict__ out, int ldo,
    int R, int G, int Kd, int relu,
    const int* __restrict__ gather, int gstep)
{
  __shared__ short As[64][40];
  __shared__ short Bs[64][40];
  int tid = threadIdx.x;
  int r0 = blockIdx.x*64, g0 = blockIdx.y*64;
  int srow = tid>>2, ks = (tid&3)*8;
  int lane = tid&63, w = tid>>6;
  int wm = (w>>1)*32, wn = (w&1)*32;
  int l15 = lane&15, lk = (lane>>4)*8;
  f4 acc[2][2] = {};
  if (A != nullptr){
    const float* ap = nullptr;
    int rr = r0 + srow;
    if (rr < R){ long ar = gather ? (long)gather[(long)rr*gstep] : (long)rr; ap = A + ar*lda; }
    int gg = g0 + srow;
    const float* wp = (!WKG && gg < G) ? (Wm + (long)gg*Kd) : nullptr;
    for (int k0 = 0; k0 < Kd; k0 += 32){
      bh8 va, vb;
#pragma unroll
      for (int q=0;q<8;q++){
        int k = k0 + ks + q;
        float fa = (ap && k < Kd) ? ap[k] : 0.f;
        float fb = 0.f;
        if (k < Kd && gg < G) fb = WKG ? Wm[(long)k*G + gg] : (wp ? wp[k] : 0.f);
        va[q] = (short)f2b(fa);
        vb[q] = (short)f2b(fb);
      }
      *(bh8*)&As[srow][ks] = va;
      *(bh8*)&Bs[srow][ks] = vb;
      __syncthreads();
      bh8 af[2], bw[2];
#pragma unroll
      for (int i=0;i<2;i++){
        af[i] = *(bh8*)&As[wm + i*16 + l15][lk];
        bw[i] = *(bh8*)&Bs[wn + i*16 + l15][lk];
      }
#pragma unroll
      for (int i=0;i<2;i++)
#pragma unroll
        for (int j=0;j<2;j++)
          acc[i][j] = __builtin_amdgcn_mfma_f32_16x16x32_bf16(af[i], bw[j], acc[i][j], 0,0,0);
      __syncthreads();
    }
  }
#pragma unroll
  for (int i=0;i<2;i++)
#pragma unroll
    for (int j=0;j<2;j++)
#pragma unroll
      for (int q=0;q<4;q++){
        int r = r0 + wm + i*16 + (lane>>4)*4 + q;
        int g = g0 + wn + j*16 + l15;
        if (r < R && g < G){
          float v = acc[i][j][q] + (bias ? bias[g] : 0.f);
          if (relu) v = fmaxf(v, 0.f);
          long off = (long)r*ldo + g;
          if (OUTB) ((unsigned short*)out)[off] = f2b(v);
          else      ((float*)out)[off] = v;
        }
      }
}

// ---------------- GRU gate fusion (xg precomputed for all t, bf16) ----------------
__global__ void gru_gate_k(const unsigned short* __restrict__ xg, const float* __restrict__ gh,
                           float* __restrict__ seq, int t, int N, int T){
  long idx = (long)blockIdx.x*256 + threadIdx.x;
  if (idx >= (long)N*H_) return;
  int n = (int)(idx >> 9); int j = (int)(idx & 511);
  const unsigned short* xp = xg + ((long)n*T + t)*1536;
  float xr = b2f(xp[j]), xz = b2f(xp[512+j]), xn = b2f(xp[1024+j]);
  long o = (long)n*1536;
  float hr = gh[o+j], hz = gh[o+512+j], hn = gh[o+1024+j];
  float r = sigf(xr+hr);
  float z = sigf(xz+hz);
  float nn = tanhf(xn + r*hn);
  float hp = (t==0) ? 0.f : seq[((long)n*T + (t-1))*H_ + j];
  seq[((long)n*T + t)*H_ + j] = (1.f - z)*nn + z*hp;
}

// ---------------- attflat score reduce: s[r] = hid[r,:]·w2 + b2 ----------------
__global__ void fsred_k(const float* __restrict__ hid, const float* __restrict__ w2,
                        const float* __restrict__ b2, float* __restrict__ s, int R){
  int r = blockIdx.x; int lane = threadIdx.x;  // 64
  const float* hp = hid + (long)r*512;
  float acc = 0.f;
  for (int j=lane;j<512;j+=64) acc += hp[j]*w2[j];
  acc = wred_sum(acc);
  if (lane==0) s[r] = acc + b2[0];
}

// ---------------- attflat softmax + weighted sum ----------------
__global__ void flat_soft_k(const float* __restrict__ s, const int* __restrict__ ix,
                            const float* __restrict__ X, float* __restrict__ outp, int T){
  int n = blockIdx.x;
  int tid = threadIdx.x;
  __shared__ float aw[64];
  if (tid < 64){
    float val = -INFINITY;
    if (tid < T) val = (ix[(long)n*T+tid]==0) ? NEG_ : s[(long)n*T+tid];
    float mx = wred_max(val);
    float e = (tid < T) ? expf(val - mx) : 0.f;
    float ssum = wred_sum(e);
    if (tid < T) aw[tid] = e/ssum;
  }
  __syncthreads();
  for (int h = tid; h < 512; h += 256){
    float acc = 0;
    for (int t=0;t<T;t++) acc += aw[t]*X[((long)n*T+t)*512 + h];
    outp[(long)n*512+h] = acc;
  }
}

// ---------------- span scores (span_p computed on the fly from cp_feat) ----------------
__global__ void sent_empty_k(const int* __restrict__ cp_ix, int* __restrict__ se){
  int i = blockIdx.x*256+threadIdx.x;
  if (i < B_*S_){ const int* p = cp_ix + (long)i*LS_; int e=1; for(int t=0;t<LS_;t++) if(p[t]!=0){e=0;break;} se[i]=e; }
}
__global__ void qdot_k(const float* __restrict__ que_vec, const float* __restrict__ scv, float* qdot){
  int b = blockIdx.x; int d = threadIdx.x;  // 128 threads
  const float* qv = que_vec + (long)b*512;
  float m = 0.25f*(qv[4*d]+qv[4*d+1]+qv[4*d+2]+qv[4*d+3]);
  float v = m*scv[d];
  __shared__ float sred[2];
  float w = wred_sum(v);
  if ((threadIdx.x&63)==0) sred[threadIdx.x>>6] = w;
  __syncthreads();
  if (threadIdx.x==0) qdot[b] = sred[0]+sred[1];
}
__global__ void que_ent_k(const float* __restrict__ que_vec, const float* __restrict__ scv,
                          const float* __restrict__ scc, float* que_ent){
  int b = blockIdx.x; int lane = threadIdx.x;  // 64
  float acc=0; for(int d=lane;d<512;d+=64) acc += que_vec[(long)b*512+d]*scv[d];
  acc = wred_sum(acc);
  if (lane==0){ float p = sigf(acc + scc[0]); que_ent[b] = entf(p); }
}
__global__ void ce_k(const float* __restrict__ cp_feat,
                     const float* __restrict__ qdot, const float* __restrict__ scv,
                     const float* __restrict__ scc, float* __restrict__ ce){
  int bj = blockIdx.x;  // 64*150
  int b = bj/150, j = bj%150;
  int sI = j/3, wi = j%3;
  int lane = threadIdx.x;  // 64
  float dsp = 0.f;
  for (int e=lane; e<1536; e+=64){
    int off = e >> 9; int dd = e & 511;
    if (off <= wi && sI+off < S_)
      dsp += cp_feat[((long)(b*S_ + sI+off))*512 + dd] * scv[e/3];
  }
  float dqe = 0.f;
  for (int d=128+lane; d<512; d+=64){
    int e0 = 4*d - 512;
    int off = e0 >> 9; int dd = e0 & 511;
    float m = 0.f;
    if (off <= wi && sI+off < S_){
      const float* cf = cp_feat + ((long)(b*S_ + sI+off))*512 + dd;
      m = 0.25f*(cf[0]+cf[1]+cf[2]+cf[3]);
    }
    dqe += m*scv[d];
  }
  dsp = wred_sum(dsp)*(1.f/3.f); dqe = wred_sum(dqe);
  if (lane==0){
    float evi = sigf(dsp + scc[0]);
    float pq  = sigf(dqe + qdot[b] + scc[0]);
    ce[bj] = evi * entf(pq);
  }
}
__global__ void argmax_k(const float* __restrict__ ce, const float* __restrict__ que_ent,
                         const int* __restrict__ sent_e, const float* __restrict__ cp_feat,
                         float* __restrict__ evi_feat){
  int b = blockIdx.x;
  __shared__ int bix;
  if (threadIdx.x==0){
    float best = -INFINITY; int bidx = 0;
    for (int j=0;j<150;j++){
      float v = sent_e[b*S_ + j/3] ? NEG_ : (que_ent[b] - ce[b*150+j]);
      if (v > best){ best = v; bidx = j; }
    }
    bix = bidx;
  }
  __syncthreads();
  int sI = bix/3, wi = bix%3;
  for (int d=threadIdx.x; d<512; d+=blockDim.x){
    float sum = 0.f;
#pragma unroll
    for (int q=0;q<3;q++){
      int e = 3*d + q; int off = e >> 9; int dd = e & 511;
      if (off <= wi && sI+off < S_) sum += cp_feat[((long)(b*S_ + sI+off))*512 + dd];
    }
    evi_feat[(long)b*512+d] = sum * (1.f/3.f);
  }
}

// ---------------- bilinear attention ----------------
__global__ void u_k(const float* __restrict__ v_f, const float* __restrict__ hmat, float* __restrict__ u){
  int idx = blockIdx.x*256+threadIdx.x;  // 64*2*512
  if (idx >= 65536) return;
  int k = idx & 511; int g = (idx >> 9) & 1; int b = idx >> 10;
  u[idx] = v_f[(long)b*512+k]*hmat[(long)g*512+k];
}
__global__ void att_k(const float* __restrict__ u, const float* __restrict__ q_,
                      const float* __restrict__ hbias, float* __restrict__ att){
  int bg = blockIdx.x;  // 128
  int b = bg >> 1, g = bg & 1;
  int lane = threadIdx.x;  // 64
  const float* up = u + (long)bg*512;
  const float* qp = q_ + ((long)b*64 + lane)*512;
  float dot = 0;
  for (int k=0;k<512;k++) dot += up[k]*qp[k];
  dot += hbias[g];
  float mx = wred_max(dot);
  float e = expf(dot - mx);
  float ssum = wred_sum(e);
  att[(long)bg*64 + lane] = e/ssum;
}
__global__ void bi_k(const float* __restrict__ att, const float* __restrict__ vg,
                     const float* __restrict__ qg, float* __restrict__ bi, int g){
  int b = blockIdx.x; int k = threadIdx.x;  // 512
  __shared__ float a[64];
  if (k < 64) a[k] = att[((long)b*2+g)*64 + k];
  __syncthreads();
  float acc = 0;
  for (int q=0;q<64;q++) acc += a[q]*qg[((long)b*64+q)*512 + k];
  bi[(long)b*512+k] = vg[(long)b*512+k]*acc;
}
__global__ void addq_k(float* __restrict__ q, const float* __restrict__ upd){
  long idx = (long)blockIdx.x*256 + threadIdx.x;  // 64*64*512
  if (idx >= 64L*64*512) return;
  int h = (int)(idx & 511); int b = (int)(idx >> 15);
  q[idx] += upd[(long)b*512 + h];
}
__global__ void meanq_k(const float* __restrict__ q, float* __restrict__ fq){
  int b = blockIdx.x; int h = threadIdx.x;  // 512
  float acc=0; for(int t=0;t<64;t++) acc += q[((long)b*64+t)*512+h];
  fq[(long)b*512+h] = acc*(1.f/64.f);
}

// ---------------- classifier ----------------
__global__ void fuse_k(const float* __restrict__ que_vec, const float* __restrict__ opt_feat,
                       const float* __restrict__ evi_feat, const float* __restrict__ fuse_qe,
                       float* __restrict__ fuse){
  long idx = (long)blockIdx.x*256+threadIdx.x;  // 448*4096
  if (idx >= 448L*4096) return;
  int e = (int)(idx & 4095); long r = idx >> 12;
  int c = e >> 9, d = e & 511;
  int b = (int)(r / 7);
  float qv = que_vec[(long)b*512+d], ov = opt_feat[r*512+d], ev = evi_feat[(long)b*512+d], fq = fuse_qe[(long)b*512+d];
  float val;
  switch(c){
    case 0: val=qv; break; case 1: val=ov; break; case 2: val=ev; break;
    case 3: val=qv*ev; break; case 4: val=ev*ov; break; case 5: val=qv*ov; break;
    case 6: val=fq; break; default: val=qv*ov*fq; break;
  }
  fuse[idx]=val;
}
__global__ void cls_final_k(const float* __restrict__ clsh, const float* __restrict__ cls_w2,
                            const float* __restrict__ cls_b2, const int* __restrict__ opt_ix,
                            float* __restrict__ outp){
  int r = blockIdx.x;  // 448
  int lane = threadIdx.x;  // 64
  float acc=0;
  for (int j=lane;j<512;j+=64) acc += clsh[(long)r*512+j]*cls_w2[j];
  acc = wred_sum(acc);
  if (lane==0){
    bool empty = true;
    for (int t=0;t<LO_;t++) if (opt_ix[(long)r*LO_+t]!=0) { empty=false; break; }
    outp[r] = empty ? NEG_ : (acc + cls_b2[0]);
  }
}
__global__ void count_k(const int* __restrict__ opt_ix, float* __restrict__ outp){
  int b = threadIdx.x;  // 64
  if (b < B_){
    int c=0;
    for(int a=0;a<A_;a++){
      bool e=true;
      for(int t=0;t<LO_;t++) if(opt_ix[((long)b*A_+a)*LO_+t]!=0){e=false;break;}
      if (!e) c++;
    }
    outp[448+b]=(float)c;
  }
}

// ---------------- host orchestration ----------------
static size_t total_need(long Nc){
  long tokmax = (Nc*32 > 7168) ? Nc*32 : 7168;
  long Nmax = Nc > 448 ? Nc : 448;
  size_t s = 0;
  s += 64L*64*512;            // que_seq
  s += 448L*16*512;           // opt_seq
  s += (size_t)Nc*32*512;     // chunk_seq
  s += (size_t)tokmax*768 + 16; // xg (bf16, float-equivalents)
  s += (size_t)Nmax*1536;     // gh
  s += (size_t)tokmax*512;    // hid
  s += 512 + 8;               // scv, scc
  s += (size_t)tokmax;        // sbuf
  s += (size_t)Nmax*512;      // pre
  s += 3200L*512;             // cp_feat
  s += 448L*512;              // opt_feat
  s += 64L*512;               // que_vec
  s += 64 + 64 + 9600 + 3200; // qdot, que_ent, ce, sent_e
  s += 64L*512;               // evi_feat
  s += 4096L*512;             // q_
  s += 128L*512 + 128L*64;    // u, att
  s += 64L*512*2;             // v_f, vg
  s += 4096L*512;             // qg
  s += 64L*512*3;             // bi, upd, fuse_qe
  s += 448L*4096;             // fuse
  s += 448L*512;              // clsh
  return s;
}

extern "C" void kernel_launch(void* const* d_in, const int* in_sizes, int n_in,
                              void* d_out, int out_size, void* d_ws, size_t ws_size,
                              hipStream_t stream) {
  const int*   que_ix  = (const int*)d_in[0];
  const int*   opt_ix  = (const int*)d_in[1];
  const int*   cp_ix   = (const int*)d_in[2];
  const float* emb     = (const float*)d_in[3];
  const float* gru_wi  = (const float*)d_in[4];
  const float* gru_wh  = (const float*)d_in[5];
  const float* gru_bi  = (const float*)d_in[6];
  const float* gru_bh  = (const float*)d_in[7];
  const float* flat_w1 = (const float*)d_in[8];
  const float* flat_b1 = (const float*)d_in[9];
  const float* flat_w2 = (const float*)d_in[10];
  const float* flat_b2 = (const float*)d_in[11];
  const float* flat_mw = (const float*)d_in[12];
  const float* flat_mb = (const float*)d_in[13];
  const float* score_w1= (const float*)d_in[14];
  const float* score_b1= (const float*)d_in[15];
  const float* score_w2= (const float*)d_in[16];
  const float* score_b2= (const float*)d_in[17];
  const float* ba_vw   = (const float*)d_in[18];
  const float* ba_vb   = (const float*)d_in[19];
  const float* ba_qw   = (const float*)d_in[20];
  const float* ba_qb   = (const float*)d_in[21];
  const float* ba_hmat = (const float*)d_in[22];
  const float* ba_hbias= (const float*)d_in[23];
  const float* bc_vw   = (const float*)d_in[24];
  const float* bc_vb   = (const float*)d_in[25];
  const float* bc_qw   = (const float*)d_in[26];
  const float* bc_qb   = (const float*)d_in[27];
  const float* prj_w   = (const float*)d_in[28];
  const float* prj_b   = (const float*)d_in[29];
  const float* cls_w1  = (const float*)d_in[30];
  const float* cls_b1  = (const float*)d_in[31];
  const float* cls_w2  = (const float*)d_in[32];
  const float* cls_b2  = (const float*)d_in[33];

  size_t avail = ws_size / sizeof(float);
  long Nc = 3200;
  while (Nc > 32 && total_need(Nc) > avail) Nc -= 32;

  long tokmax = (Nc*32 > 7168) ? Nc*32 : 7168;
  long Nmax = Nc > 448 ? Nc : 448;

  float* Wp = (float*)d_ws;
  size_t o = 0;
  auto F = [&](size_t n){ float* p = Wp + o; o += n; return p; };
  float* que_seq  = F(64L*64*512);
  float* opt_seq  = F(448L*16*512);
  float* chunk_seq= F((size_t)Nc*32*512);
  unsigned short* xg = (unsigned short*)F((size_t)tokmax*768 + 16);
  float* gh       = F((size_t)Nmax*1536);
  float* hid      = F((size_t)tokmax*512);
  float* scv      = F(512);
  float* scc      = F(8);
  float* sbuf     = F((size_t)tokmax);
  float* pre      = F((size_t)Nmax*512);
  float* cp_feat  = F(3200L*512);
  float* opt_feat = F(448L*512);
  float* que_vec  = F(64L*512);
  float* qdot     = F(64);
  float* que_ent  = F(64);
  float* ce       = F(9600);
  int*   sent_e   = (int*)F(3200);
  float* evi_feat = F(64L*512);
  float* q_       = F(4096L*512);
  float* u        = F(128L*512);
  float* att      = F(128L*64);
  float* v_f      = F(64L*512);
  float* vg       = F(64L*512);
  float* qg       = F(4096L*512);
  float* bi       = F(64L*512);
  float* upd      = F(64L*512);
  float* fuse_qe  = F(64L*512);
  float* fuse     = F(448L*4096);
  float* clsh     = F(448L*512);

  dim3 blk(256);
  hipLaunchKernelGGL(score_fold_k, dim3(2), blk, 0, stream, score_w1, score_b1, score_w2, score_b2, scv, scc);

  // ---- GRU: one-shot xg (all timesteps, bf16 out) + per-step recurrent GEMM + gate ----
  auto run_gru = [&](const int* ix, int N, int Tn, float* seq){
    int RT = N*Tn;
    hipLaunchKernelGGL((mgemm_k<false,true>), dim3((unsigned)((RT+63)/64), 24), blk, 0, stream,
                       emb, (long)E_, gru_wi, gru_bi, (void*)xg, 1536, RT, 1536, E_, 0, ix, 1);
    for (int t=0; t<Tn; t++){
      const float* hp = (t==0) ? nullptr : (seq + (long)(t-1)*512);
      hipLaunchKernelGGL((mgemm_k<false,false>), dim3((unsigned)((N+63)/64), 24), blk, 0, stream,
                         hp, (long)Tn*512, gru_wh, gru_bh, (void*)gh, 1536, N, 1536, 512, 0, nullptr, 0);
      long tot = (long)N*512;
      hipLaunchKernelGGL(gru_gate_k, dim3((unsigned)((tot+255)/256)), blk, 0, stream, xg, gh, seq, t, N, Tn);
    }
  };
  // ---- attflat: MFMA GEMM -> hid, reduce -> scores, softmax, MFMA mw GEMM ----
  auto run_attflat = [&](const float* seq, const int* ix, int N, int Tn, float* outfeat){
    int R = N*Tn;
    hipLaunchKernelGGL((mgemm_k<true,false>), dim3((unsigned)((R+63)/64), 8), blk, 0, stream,
                       seq, 512L, flat_w1, flat_b1, (void*)hid, 512, R, 512, 512, 1, nullptr, 0);
    hipLaunchKernelGGL(fsred_k, dim3((unsigned)R), dim3(64), 0, stream, hid, flat_w2, flat_b2, sbuf, R);
    hipLaunchKernelGGL(flat_soft_k, dim3((unsigned)N), blk, 0, stream, sbuf, ix, seq, pre, Tn);
    hipLaunchKernelGGL((mgemm_k<true,false>), dim3((unsigned)((N+63)/64), 8), blk, 0, stream,
                       pre, 512L, flat_mw, flat_mb, (void*)outfeat, 512, N, 512, 512, 0, nullptr, 0);
  };

  run_gru(que_ix, 64, 64, que_seq);
  run_attflat(que_seq, que_ix, 64, 64, que_vec);
  run_gru(opt_ix, 448, 16, opt_seq);
  run_attflat(opt_seq, opt_ix, 448, 16, opt_feat);
  for (long start = 0; start < 3200; start += Nc){
    long Ncur = (3200 - start < Nc) ? (3200 - start) : Nc;
    run_gru(cp_ix + start*32, (int)Ncur, 32, chunk_seq);
    run_attflat(chunk_seq, cp_ix + start*32, (int)Ncur, 32, cp_feat + start*512);
  }

  // ---- span scores + info gain + evidence ----
  hipLaunchKernelGGL(sent_empty_k, dim3((B_*S_+255)/256), blk, 0, stream, cp_ix, sent_e);
  hipLaunchKernelGGL(qdot_k, dim3(64), dim3(128), 0, stream, que_vec, scv, qdot);
  hipLaunchKernelGGL(que_ent_k, dim3(64), dim3(64), 0, stream, que_vec, scv, scc, que_ent);
  hipLaunchKernelGGL(ce_k, dim3(64*150), dim3(64), 0, stream, cp_feat, qdot, scv, scc, ce);
  hipLaunchKernelGGL(argmax_k, dim3(64), dim3(256), 0, stream, ce, que_ent, sent_e, cp_feat, evi_feat);

  // ---- bilinear attention fusion ----
  hipLaunchKernelGGL((mgemm_k<true,false>), dim3(1, 8), blk, 0, stream,
                     evi_feat, 512L, ba_vw, ba_vb, (void*)v_f, 512, 64, 512, 512, 1, nullptr, 0);
  hipLaunchKernelGGL((mgemm_k<true,false>), dim3(64, 8), blk, 0, stream,
                     que_seq, 512L, ba_qw, ba_qb, (void*)q_, 512, 4096, 512, 512, 1, nullptr, 0);
  hipLaunchKernelGGL(u_k, dim3(65536/256), blk, 0, stream, v_f, ba_hmat, u);
  hipLaunchKernelGGL(att_k, dim3(128), dim3(64), 0, stream, u, q_, ba_hbias, att);
  for (int g=0; g<2; g++){
    hipLaunchKernelGGL((mgemm_k<true,false>), dim3(64, 8), blk, 0, stream,
                       que_seq, 512L, bc_qw + (long)g*512*512, bc_qb + (long)g*512, (void*)qg, 512, 4096, 512, 512, 1, nullptr, 0);
    hipLaunchKernelGGL((mgemm_k<true,false>), dim3(1, 8), blk, 0, stream,
                       evi_feat, 512L, bc_vw + (long)g*512*512, bc_vb + (long)g*512, (void*)vg, 512, 64, 512, 512, 1, nullptr, 0);
    hipLaunchKernelGGL(bi_k, dim3(64), dim3(512), 0, stream, att, vg, qg, bi, g);
    hipLaunchKernelGGL((mgemm_k<true,false>), dim3(1, 8), blk, 0, stream,
                       bi, 512L, prj_w + (long)g*512*512, prj_b + (long)g*512, (void*)upd, 512, 64, 512, 512, 0, nullptr, 0);
    hipLaunchKernelGGL(addq_k, dim3((unsigned)((64L*64*512+255)/256)), blk, 0, stream, que_seq, upd);
  }
  hipLaunchKernelGGL(meanq_k, dim3(64), dim3(512), 0, stream, que_seq, fuse_qe);

  // ---- classifier ----
  hipLaunchKernelGGL(fuse_k, dim3((unsigned)((448L*4096+255)/256)), blk, 0, stream, que_vec, opt_feat, evi_feat, fuse_qe, fuse);
  hipLaunchKernelGGL((mgemm_k<true,false>), dim3(7, 8), blk, 0, stream,
                     fuse, 4096L, cls_w1, cls_b1, (void*)clsh, 512, 448, 512, 4096, 1, nullptr, 0);
  hipLaunchKernelGGL(cls_final_k, dim3(448), dim3(64), 0, stream, clsh, cls_w2, cls_b2, opt_ix, (float*)d_out);
  hipLaunchKernelGGL(count_k, dim3(1), dim3(64), 0, stream, opt_ix, (float*)d_out);
}

// Round 9
// 3952.368 us; speedup vs baseline: 5.9152x; 3.8930x over previous
//
#include <hip/hip_runtime.h>
#include <hip/hip_bf16.h>
#include <cmath>

#define NEG_ (-1000000000.0f)

// dims
#define V_ 30000
#define E_ 300
#define EP_ 320
#define H_ 512
#define B_ 64
#define LQ_ 64
#define A_ 7
#define LO_ 16
#define S_ 50
#define LS_ 32
#define W_ 3

typedef __attribute__((ext_vector_type(8))) short bh8;
typedef __attribute__((ext_vector_type(4))) float f4;

__device__ __forceinline__ float wred_sum(float v){
#pragma unroll
  for (int o=32;o>0;o>>=1) v += __shfl_xor(v,o);
  return v;
}
__device__ __forceinline__ float wred_max(float v){
#pragma unroll
  for (int o=32;o>0;o>>=1) v = fmaxf(v,__shfl_xor(v,o));
  return v;
}
__device__ __forceinline__ float sigf(float x){ return 1.f/(1.f+expf(-x)); }
__device__ __forceinline__ float entf(float p){ return -(p*log2f(p) + (1.f-p)*log2f(1.f-p)); }
__device__ __forceinline__ unsigned short f2b(float f){
  unsigned x = __float_as_uint(f);
  x = x + 0x7FFF + ((x>>16)&1);
  return (unsigned short)(x>>16);
}
__device__ __forceinline__ float b2f(unsigned short u){
  return __uint_as_float(((unsigned)u)<<16);
}

// ---------------- weight conversion ----------------
// f32 [G][K] -> bf16 [G][Kp], zero-padded K..Kp
__global__ void cvt_gk_k(const float* __restrict__ in, unsigned short* __restrict__ out,
                         int G, int K, int Kp){
  long idx = (long)blockIdx.x*256 + threadIdx.x;
  if (idx >= (long)G*Kp) return;
  int k = (int)(idx % Kp); long g = idx / Kp;
  out[idx] = (k < K) ? f2b(in[g*K + k]) : 0;
}
// f32 [K][G] -> bf16 [G][Kp] (transpose)
__global__ void cvt_kg_k(const float* __restrict__ in, unsigned short* __restrict__ out,
                         int G, int K, int Kp){
  long idx = (long)blockIdx.x*256 + threadIdx.x;
  if (idx >= (long)G*Kp) return;
  int k = (int)(idx % Kp); long g = idx / Kp;
  out[idx] = (k < K) ? f2b(in[(long)k*G + g]) : 0;
}

__global__ void score_fold_k(const float* __restrict__ w1, const float* __restrict__ b1,
                             const float* __restrict__ w2, const float* __restrict__ b2,
                             float* scv, float* scc){
  int k = blockIdx.x*256+threadIdx.x;
  if (k < H_){ float s=0; for(int j=0;j<H_;j++) s += w1[(long)k*H_+j]*w2[j]; scv[k]=s; }
  if (blockIdx.x==0 && threadIdx.x==0){ float s=0; for(int j=0;j<H_;j++) s += b1[j]*w2[j]; *scc = s + b2[0]; }
}

// ---------------- all-bf16 MFMA GEMM ----------------
// out[r,g] = bias[g] + sum_k A_row(r)[k] * W[g][k];  A bf16 [*, lda], W bf16 [G][Kd], Kd%32==0.
// A row: gather ? A + gather[r*gstep]*lda : A + r*lda.  A==null -> acc 0 (out = bias).
// 64x64 tile, 4 waves (2x2 of 32x32), 2x2 mfma_f32_16x16x32_bf16 frags each.
// LDS [64][40] bf16 (pad 8 shorts -> ~2-way bank alias, free).  Frag read = one b128.
// C/D: col = lane&15, row = (lane>>4)*4 + reg  [HW-verified round 8].
template<bool OUTB>
__global__ __launch_bounds__(256) void mgemm_b(
    const unsigned short* __restrict__ A, long lda,
    const unsigned short* __restrict__ Wm, const float* __restrict__ bias,
    void* __restrict__ out, int ldo,
    int R, int G, int Kd, int relu,
    const int* __restrict__ gather, int gstep)
{
  __shared__ short As[64][40];
  __shared__ short Bs[64][40];
  int tid = threadIdx.x;
  int r0 = blockIdx.x*64, g0 = blockIdx.y*64;
  int srow = tid>>2, ks = (tid&3)*8;
  int lane = tid&63, w = tid>>6;
  int wm = (w>>1)*32, wn = (w&1)*32;
  int l15 = lane&15, lk = (lane>>4)*8;
  f4 acc[2][2] = {};
  if (A != nullptr){
    const unsigned short* ap = nullptr;
    int rr = r0 + srow;
    if (rr < R){ long ar = gather ? (long)gather[(long)rr*gstep] : (long)rr; ap = A + ar*lda; }
    int gg = g0 + srow;
    const unsigned short* wp = (gg < G) ? (Wm + (long)gg*Kd) : nullptr;
    for (int k0 = 0; k0 < Kd; k0 += 32){
      bh8 va, vb;
#pragma unroll
      for (int q=0;q<8;q++){ va[q]=0; vb[q]=0; }
      if (ap) va = *(const bh8*)(ap + k0 + ks);
      if (wp) vb = *(const bh8*)(wp + k0 + ks);
      *(bh8*)&As[srow][ks] = va;
      *(bh8*)&Bs[srow][ks] = vb;
      __syncthreads();
      bh8 af[2], bw[2];
#pragma unroll
      for (int i=0;i<2;i++){
        af[i] = *(bh8*)&As[wm + i*16 + l15][lk];
        bw[i] = *(bh8*)&Bs[wn + i*16 + l15][lk];
      }
#pragma unroll
      for (int i=0;i<2;i++)
#pragma unroll
        for (int j=0;j<2;j++)
          acc[i][j] = __builtin_amdgcn_mfma_f32_16x16x32_bf16(af[i], bw[j], acc[i][j], 0,0,0);
      __syncthreads();
    }
  }
#pragma unroll
  for (int i=0;i<2;i++)
#pragma unroll
    for (int j=0;j<2;j++)
#pragma unroll
      for (int q=0;q<4;q++){
        int r = r0 + wm + i*16 + (lane>>4)*4 + q;
        int g = g0 + wn + j*16 + l15;
        if (r < R && g < G){
          float v = acc[i][j][q] + (bias ? bias[g] : 0.f);
          if (relu) v = fmaxf(v, 0.f);
          long off = (long)r*ldo + g;
          if (OUTB) ((unsigned short*)out)[off] = f2b(v);
          else      ((float*)out)[off] = v;
        }
      }
}

// ---------------- GRU gate fusion (bf16 xg + bf16 h-state) ----------------
__global__ void gru_gate_k(const unsigned short* __restrict__ xg, const float* __restrict__ gh,
                           unsigned short* __restrict__ seq, int t, int N, int T){
  long idx = (long)blockIdx.x*256 + threadIdx.x;
  if (idx >= (long)N*H_) return;
  int n = (int)(idx >> 9); int j = (int)(idx & 511);
  const unsigned short* xp = xg + ((long)n*T + t)*1536;
  float xr = b2f(xp[j]), xz = b2f(xp[512+j]), xn = b2f(xp[1024+j]);
  long o = (long)n*1536;
  float hr = gh[o+j], hz = gh[o+512+j], hn = gh[o+1024+j];
  float r = sigf(xr+hr);
  float z = sigf(xz+hz);
  float nn = tanhf(xn + r*hn);
  float hp = (t==0) ? 0.f : b2f(seq[((long)n*T + (t-1))*H_ + j]);
  seq[((long)n*T + t)*H_ + j] = f2b((1.f - z)*nn + z*hp);
}

// ---------------- attflat score reduce: s[r] = hid[r,:]·w2 + b2  (hid bf16) ----------------
__global__ void fsred_k(const unsigned short* __restrict__ hid, const float* __restrict__ w2,
                        const float* __restrict__ b2, float* __restrict__ s, int R){
  int r = blockIdx.x; int lane = threadIdx.x;  // 64
  bh8 v = *(const bh8*)(hid + (long)r*512 + lane*8);
  float acc = 0.f;
#pragma unroll
  for (int q=0;q<8;q++) acc += b2f((unsigned short)v[q]) * w2[lane*8+q];
  acc = wred_sum(acc);
  if (lane==0) s[r] = acc + b2[0];
}

// ---------------- attflat softmax + weighted sum (X bf16, out bf16) ----------------
__global__ void flat_soft_k(const float* __restrict__ s, const int* __restrict__ ix,
                            const unsigned short* __restrict__ X, unsigned short* __restrict__ outp, int T){
  int n = blockIdx.x;
  int tid = threadIdx.x;
  __shared__ float aw[64];
  if (tid < 64){
    float val = -INFINITY;
    if (tid < T) val = (ix[(long)n*T+tid]==0) ? NEG_ : s[(long)n*T+tid];
    float mx = wred_max(val);
    float e = (tid < T) ? expf(val - mx) : 0.f;
    float ssum = wred_sum(e);
    if (tid < T) aw[tid] = e/ssum;
  }
  __syncthreads();
  for (int h = tid; h < 512; h += 256){
    float acc = 0;
    for (int t=0;t<T;t++) acc += aw[t]*b2f(X[((long)n*T+t)*512 + h]);
    outp[(long)n*512+h] = f2b(acc);
  }
}

// ---------------- span scores ----------------
__global__ void sent_empty_k(const int* __restrict__ cp_ix, int* __restrict__ se){
  int i = blockIdx.x*256+threadIdx.x;
  if (i < B_*S_){ const int* p = cp_ix + (long)i*LS_; int e=1; for(int t=0;t<LS_;t++) if(p[t]!=0){e=0;break;} se[i]=e; }
}
__global__ void qdot_k(const float* __restrict__ que_vec, const float* __restrict__ scv, float* qdot){
  int b = blockIdx.x; int d = threadIdx.x;  // 128 threads
  const float* qv = que_vec + (long)b*512;
  float m = 0.25f*(qv[4*d]+qv[4*d+1]+qv[4*d+2]+qv[4*d+3]);
  float v = m*scv[d];
  __shared__ float sred[2];
  float w = wred_sum(v);
  if ((threadIdx.x&63)==0) sred[threadIdx.x>>6] = w;
  __syncthreads();
  if (threadIdx.x==0) qdot[b] = sred[0]+sred[1];
}
__global__ void que_ent_k(const float* __restrict__ que_vec, const float* __restrict__ scv,
                          const float* __restrict__ scc, float* que_ent){
  int b = blockIdx.x; int lane = threadIdx.x;  // 64
  float acc=0; for(int d=lane;d<512;d+=64) acc += que_vec[(long)b*512+d]*scv[d];
  acc = wred_sum(acc);
  if (lane==0){ float p = sigf(acc + scc[0]); que_ent[b] = entf(p); }
}
__global__ void ce_k(const float* __restrict__ cp_feat,
                     const float* __restrict__ qdot, const float* __restrict__ scv,
                     const float* __restrict__ scc, float* __restrict__ ce){
  int bj = blockIdx.x;  // 64*150
  int b = bj/150, j = bj%150;
  int sI = j/3, wi = j%3;
  int lane = threadIdx.x;  // 64
  float dsp = 0.f;
  for (int e=lane; e<1536; e+=64){
    int off = e >> 9; int dd = e & 511;
    if (off <= wi && sI+off < S_)
      dsp += cp_feat[((long)(b*S_ + sI+off))*512 + dd] * scv[e/3];
  }
  float dqe = 0.f;
  for (int d=128+lane; d<512; d+=64){
    int e0 = 4*d - 512;
    int off = e0 >> 9; int dd = e0 & 511;
    float m = 0.f;
    if (off <= wi && sI+off < S_){
      const float* cf = cp_feat + ((long)(b*S_ + sI+off))*512 + dd;
      m = 0.25f*(cf[0]+cf[1]+cf[2]+cf[3]);
    }
    dqe += m*scv[d];
  }
  dsp = wred_sum(dsp)*(1.f/3.f); dqe = wred_sum(dqe);
  if (lane==0){
    float evi = sigf(dsp + scc[0]);
    float pq  = sigf(dqe + qdot[b] + scc[0]);
    ce[bj] = evi * entf(pq);
  }
}
__global__ void argmax_k(const float* __restrict__ ce, const float* __restrict__ que_ent,
                         const int* __restrict__ sent_e, const float* __restrict__ cp_feat,
                         float* __restrict__ evi_feat, unsigned short* __restrict__ evi_b){
  int b = blockIdx.x;
  __shared__ int bix;
  if (threadIdx.x==0){
    float best = -INFINITY; int bidx = 0;
    for (int j=0;j<150;j++){
      float v = sent_e[b*S_ + j/3] ? NEG_ : (que_ent[b] - ce[b*150+j]);
      if (v > best){ best = v; bidx = j; }
    }
    bix = bidx;
  }
  __syncthreads();
  int sI = bix/3, wi = bix%3;
  for (int d=threadIdx.x; d<512; d+=blockDim.x){
    float sum = 0.f;
#pragma unroll
    for (int q=0;q<3;q++){
      int e = 3*d + q; int off = e >> 9; int dd = e & 511;
      if (off <= wi && sI+off < S_) sum += cp_feat[((long)(b*S_ + sI+off))*512 + dd];
    }
    float v = sum * (1.f/3.f);
    evi_feat[(long)b*512+d] = v;
    evi_b[(long)b*512+d] = f2b(v);
  }
}

// ---------------- bilinear attention ----------------
__global__ void u_k(const float* __restrict__ v_f, const float* __restrict__ hmat, float* __restrict__ u){
  int idx = blockIdx.x*256+threadIdx.x;  // 64*2*512
  if (idx >= 65536) return;
  int k = idx & 511; int g = (idx >> 9) & 1; int b = idx >> 10;
  u[idx] = v_f[(long)b*512+k]*hmat[(long)g*512+k];
}
__global__ void att_k(const float* __restrict__ u, const float* __restrict__ q_,
                      const float* __restrict__ hbias, float* __restrict__ att){
  int bg = blockIdx.x;  // 128
  int b = bg >> 1, g = bg & 1;
  int lane = threadIdx.x;  // 64
  const float* up = u + (long)bg*512;
  const float* qp = q_ + ((long)b*64 + lane)*512;
  float dot = 0;
  for (int k=0;k<512;k++) dot += up[k]*qp[k];
  dot += hbias[g];
  float mx = wred_max(dot);
  float e = expf(dot - mx);
  float ssum = wred_sum(e);
  att[(long)bg*64 + lane] = e/ssum;
}
__global__ void bi_k(const float* __restrict__ att, const float* __restrict__ vg,
                     const float* __restrict__ qg, unsigned short* __restrict__ bi, int g){
  int b = blockIdx.x; int k = threadIdx.x;  // 512
  __shared__ float a[64];
  if (k < 64) a[k] = att[((long)b*2+g)*64 + k];
  __syncthreads();
  float acc = 0;
  for (int q=0;q<64;q++) acc += a[q]*qg[((long)b*64+q)*512 + k];
  bi[(long)b*512+k] = f2b(vg[(long)b*512+k]*acc);
}
__global__ void addq_k(unsigned short* __restrict__ q, const float* __restrict__ upd){
  long idx = (long)blockIdx.x*256 + threadIdx.x;  // 64*64*512
  if (idx >= 64L*64*512) return;
  int h = (int)(idx & 511); int b = (int)(idx >> 15);
  q[idx] = f2b(b2f(q[idx]) + upd[(long)b*512 + h]);
}
__global__ void meanq_k(const unsigned short* __restrict__ q, float* __restrict__ fq){
  int b = blockIdx.x; int h = threadIdx.x;  // 512
  float acc=0; for(int t=0;t<64;t++) acc += b2f(q[((long)b*64+t)*512+h]);
  fq[(long)b*512+h] = acc*(1.f/64.f);
}

// ---------------- classifier ----------------
__global__ void fuse_k(const float* __restrict__ que_vec, const float* __restrict__ opt_feat,
                       const float* __restrict__ evi_feat, const float* __restrict__ fuse_qe,
                       unsigned short* __restrict__ fuse){
  long idx = (long)blockIdx.x*256+threadIdx.x;  // 448*4096
  if (idx >= 448L*4096) return;
  int e = (int)(idx & 4095); long r = idx >> 12;
  int c = e >> 9, d = e & 511;
  int b = (int)(r / 7);
  float qv = que_vec[(long)b*512+d], ov = opt_feat[r*512+d], ev = evi_feat[(long)b*512+d], fq = fuse_qe[(long)b*512+d];
  float val;
  switch(c){
    case 0: val=qv; break; case 1: val=ov; break; case 2: val=ev; break;
    case 3: val=qv*ev; break; case 4: val=ev*ov; break; case 5: val=qv*ov; break;
    case 6: val=fq; break; default: val=qv*ov*fq; break;
  }
  fuse[idx]=f2b(val);
}
__global__ void cls_final_k(const float* __restrict__ clsh, const float* __restrict__ cls_w2,
                            const float* __restrict__ cls_b2, const int* __restrict__ opt_ix,
                            float* __restrict__ outp){
  int r = blockIdx.x;  // 448
  int lane = threadIdx.x;  // 64
  float acc=0;
  for (int j=lane;j<512;j+=64) acc += clsh[(long)r*512+j]*cls_w2[j];
  acc = wred_sum(acc);
  if (lane==0){
    bool empty = true;
    for (int t=0;t<LO_;t++) if (opt_ix[(long)r*LO_+t]!=0) { empty=false; break; }
    outp[r] = empty ? NEG_ : (acc + cls_b2[0]);
  }
}
__global__ void count_k(const int* __restrict__ opt_ix, float* __restrict__ outp){
  int b = threadIdx.x;  // 64
  if (b < B_){
    int c=0;
    for(int a=0;a<A_;a++){
      bool e=true;
      for(int t=0;t<LO_;t++) if(opt_ix[((long)b*A_+a)*LO_+t]!=0){e=false;break;}
      if (!e) c++;
    }
    outp[448+b]=(float)c;
  }
}

// ---------------- host orchestration ----------------
static size_t total_need(long Nc){
  long tok = Nc*32; if (tok < 7168) tok = 7168;
  long Nmax = Nc > 448 ? Nc : 448;
  size_t s = 0;
  s += 64L*64*256;          // que_seq_b (float-equiv of bf16)
  s += 448L*16*256;         // opt_seq_b
  s += (size_t)Nc*32*256;   // chunk_seq_b
  s += (size_t)tok*768;     // xg_b
  s += (size_t)Nmax*1536;   // gh (f32)
  s += (size_t)tok*256;     // hid_b
  s += 30000L*160;          // emb_b
  s += 3400000;             // bf16 weights (~3.3M fl)
  s += 1024;                // scv/scc
  s += (size_t)tok;         // sbuf
  s += (size_t)Nmax*256;    // pre_b
  s += 3200L*512 + 448L*512 + 64L*512;  // cp_feat, opt_feat, que_vec
  s += 16384;               // qdot/que_ent/ce/sent_e
  s += 64L*512 + 64L*256;   // evi_feat f32 + evi_b
  s += 4096L*512*2;         // q_, qg
  s += 128L*512 + 128L*64;  // u, att
  s += 64L*512*4;           // v_f, vg, upd, fuse_qe
  s += 64L*256;             // bi_b
  s += 448L*2048;           // fuse_b
  s += 448L*512;            // clsh
  s += 2048;                // alignment slack
  return s;
}

extern "C" void kernel_launch(void* const* d_in, const int* in_sizes, int n_in,
                              void* d_out, int out_size, void* d_ws, size_t ws_size,
                              hipStream_t stream) {
  const int*   que_ix  = (const int*)d_in[0];
  const int*   opt_ix  = (const int*)d_in[1];
  const int*   cp_ix   = (const int*)d_in[2];
  const float* emb     = (const float*)d_in[3];
  const float* gru_wi  = (const float*)d_in[4];
  const float* gru_wh  = (const float*)d_in[5];
  const float* gru_bi  = (const float*)d_in[6];
  const float* gru_bh  = (const float*)d_in[7];
  const float* flat_w1 = (const float*)d_in[8];
  const float* flat_b1 = (const float*)d_in[9];
  const float* flat_w2 = (const float*)d_in[10];
  const float* flat_b2 = (const float*)d_in[11];
  const float* flat_mw = (const float*)d_in[12];
  const float* flat_mb = (const float*)d_in[13];
  const float* score_w1= (const float*)d_in[14];
  const float* score_b1= (const float*)d_in[15];
  const float* score_w2= (const float*)d_in[16];
  const float* score_b2= (const float*)d_in[17];
  const float* ba_vw   = (const float*)d_in[18];
  const float* ba_vb   = (const float*)d_in[19];
  const float* ba_qw   = (const float*)d_in[20];
  const float* ba_qb   = (const float*)d_in[21];
  const float* ba_hmat = (const float*)d_in[22];
  const float* ba_hbias= (const float*)d_in[23];
  const float* bc_vw   = (const float*)d_in[24];
  const float* bc_vb   = (const float*)d_in[25];
  const float* bc_qw   = (const float*)d_in[26];
  const float* bc_qb   = (const float*)d_in[27];
  const float* prj_w   = (const float*)d_in[28];
  const float* prj_b   = (const float*)d_in[29];
  const float* cls_w1  = (const float*)d_in[30];
  const float* cls_b1  = (const float*)d_in[31];
  const float* cls_w2  = (const float*)d_in[32];
  const float* cls_b2  = (const float*)d_in[33];

  size_t avail = ws_size / sizeof(float);
  long Nc = 3200;
  while (Nc > 32 && total_need(Nc) > avail) Nc -= 32;

  long tok = Nc*32 > 7168 ? Nc*32 : 7168;
  long Nmax = Nc > 448 ? Nc : 448;

  float* Wp = (float*)d_ws;
  size_t o = 0;
  auto F  = [&](size_t n){ o = (o+3)&~(size_t)3; float* p = Wp + o; o += n; return p; };
  auto FS = [&](size_t nsh){ return (unsigned short*)F((nsh+1)/2); };

  unsigned short* que_seq  = FS(64L*64*512);
  unsigned short* opt_seq  = FS(448L*16*512);
  unsigned short* chunk_seq= FS((size_t)Nc*32*512);
  unsigned short* xg       = FS((size_t)tok*1536);
  float*          gh       = F((size_t)Nmax*1536);
  unsigned short* hid      = FS((size_t)tok*512);
  unsigned short* emb_b    = FS(30000L*EP_);
  unsigned short* wi_b     = FS(1536L*EP_);
  unsigned short* wh_b     = FS(1536L*512);
  unsigned short* w1T_b    = FS(512L*512);
  unsigned short* mwT_b    = FS(512L*512);
  unsigned short* vwT_b    = FS(512L*512);
  unsigned short* qwT_b    = FS(512L*512);
  unsigned short* bcvT_b   = FS(2L*512*512);
  unsigned short* bcqT_b   = FS(2L*512*512);
  unsigned short* prjT_b   = FS(2L*512*512);
  unsigned short* clsT_b   = FS(512L*4096);
  float* scv      = F(512);
  float* scc      = F(8);
  float* sbuf     = F((size_t)tok);
  unsigned short* pre_b = FS((size_t)Nmax*512);
  float* cp_feat  = F(3200L*512);
  float* opt_feat = F(448L*512);
  float* que_vec  = F(64L*512);
  float* qdot     = F(64);
  float* que_ent  = F(64);
  float* ce       = F(9600);
  int*   sent_e   = (int*)F(3200);
  float* evi_feat = F(64L*512);
  unsigned short* evi_b = FS(64L*512);
  float* q_       = F(4096L*512);
  float* u        = F(128L*512);
  float* att      = F(128L*64);
  float* v_f      = F(64L*512);
  float* vg       = F(64L*512);
  float* qg       = F(4096L*512);
  unsigned short* bi_b = FS(64L*512);
  float* upd      = F(64L*512);
  float* fuse_qe  = F(64L*512);
  unsigned short* fuse_b = FS(448L*4096);
  float* clsh     = F(448L*512);

  dim3 blk(256);
  auto CVT = [&](const float* in, unsigned short* out, int G, int K, int Kp, bool kg){
    long n = (long)G*Kp;
    if (kg) hipLaunchKernelGGL(cvt_kg_k, dim3((unsigned)((n+255)/256)), blk, 0, stream, in, out, G, K, Kp);
    else    hipLaunchKernelGGL(cvt_gk_k, dim3((unsigned)((n+255)/256)), blk, 0, stream, in, out, G, K, Kp);
  };
  // weight prep (one-time per call)
  CVT(emb,     emb_b, 30000, E_, EP_, false);
  CVT(gru_wi,  wi_b,  1536,  E_, EP_, false);
  CVT(gru_wh,  wh_b,  1536,  512, 512, false);
  CVT(flat_w1, w1T_b, 512, 512, 512, true);
  CVT(flat_mw, mwT_b, 512, 512, 512, true);
  CVT(ba_vw,   vwT_b, 512, 512, 512, true);
  CVT(ba_qw,   qwT_b, 512, 512, 512, true);
  for (int g=0; g<2; g++){
    CVT(bc_vw + (long)g*512*512, bcvT_b + (long)g*512*512, 512, 512, 512, true);
    CVT(bc_qw + (long)g*512*512, bcqT_b + (long)g*512*512, 512, 512, 512, true);
    CVT(prj_w + (long)g*512*512, prjT_b + (long)g*512*512, 512, 512, 512, true);
  }
  CVT(cls_w1, clsT_b, 512, 4096, 4096, true);
  hipLaunchKernelGGL(score_fold_k, dim3(2), blk, 0, stream, score_w1, score_b1, score_w2, score_b2, scv, scc);

  // ---- GRU: one-shot xg + per-step recurrent GEMM + gate ----
  auto run_gru = [&](const int* ix, int N, int Tn, unsigned short* seq){
    int RT = N*Tn;
    hipLaunchKernelGGL((mgemm_b<true>), dim3((unsigned)((RT+63)/64), 24), blk, 0, stream,
                       emb_b, (long)EP_, wi_b, gru_bi, (void*)xg, 1536, RT, 1536, EP_, 0, ix, 1);
    for (int t=0; t<Tn; t++){
      const unsigned short* hp = (t==0) ? nullptr : (seq + (long)(t-1)*512);
      hipLaunchKernelGGL((mgemm_b<false>), dim3((unsigned)((N+63)/64), 24), blk, 0, stream,
                         hp, (long)Tn*512, wh_b, gru_bh, (void*)gh, 1536, N, 1536, 512, 0, nullptr, 0);
      long totn = (long)N*512;
      hipLaunchKernelGGL(gru_gate_k, dim3((unsigned)((totn+255)/256)), blk, 0, stream, xg, gh, seq, t, N, Tn);
    }
  };
  // ---- attflat ----
  auto run_attflat = [&](const unsigned short* seq, const int* ix, int N, int Tn, float* outfeat){
    int R = N*Tn;
    hipLaunchKernelGGL((mgemm_b<true>), dim3((unsigned)((R+63)/64), 8), blk, 0, stream,
                       seq, 512L, w1T_b, flat_b1, (void*)hid, 512, R, 512, 512, 1, nullptr, 0);
    hipLaunchKernelGGL(fsred_k, dim3((unsigned)R), dim3(64), 0, stream, hid, flat_w2, flat_b2, sbuf, R);
    hipLaunchKernelGGL(flat_soft_k, dim3((unsigned)N), blk, 0, stream, sbuf, ix, seq, pre_b, Tn);
    hipLaunchKernelGGL((mgemm_b<false>), dim3((unsigned)((N+63)/64), 8), blk, 0, stream,
                       pre_b, 512L, mwT_b, flat_mb, (void*)outfeat, 512, N, 512, 512, 0, nullptr, 0);
  };

  run_gru(que_ix, 64, 64, que_seq);
  run_attflat(que_seq, que_ix, 64, 64, que_vec);
  run_gru(opt_ix, 448, 16, opt_seq);
  run_attflat(opt_seq, opt_ix, 448, 16, opt_feat);
  for (long start = 0; start < 3200; start += Nc){
    long Ncur = (3200 - start < Nc) ? (3200 - start) : Nc;
    run_gru(cp_ix + start*32, (int)Ncur, 32, chunk_seq);
    run_attflat(chunk_seq, cp_ix + start*32, (int)Ncur, 32, cp_feat + start*512);
  }

  // ---- span scores + info gain + evidence ----
  hipLaunchKernelGGL(sent_empty_k, dim3((B_*S_+255)/256), blk, 0, stream, cp_ix, sent_e);
  hipLaunchKernelGGL(qdot_k, dim3(64), dim3(128), 0, stream, que_vec, scv, qdot);
  hipLaunchKernelGGL(que_ent_k, dim3(64), dim3(64), 0, stream, que_vec, scv, scc, que_ent);
  hipLaunchKernelGGL(ce_k, dim3(64*150), dim3(64), 0, stream, cp_feat, qdot, scv, scc, ce);
  hipLaunchKernelGGL(argmax_k, dim3(64), dim3(256), 0, stream, ce, que_ent, sent_e, cp_feat, evi_feat, evi_b);

  // ---- bilinear attention fusion ----
  hipLaunchKernelGGL((mgemm_b<false>), dim3(1, 8), blk, 0, stream,
                     evi_b, 512L, vwT_b, ba_vb, (void*)v_f, 512, 64, 512, 512, 1, nullptr, 0);
  hipLaunchKernelGGL((mgemm_b<false>), dim3(64, 8), blk, 0, stream,
                     que_seq, 512L, qwT_b, ba_qb, (void*)q_, 512, 4096, 512, 512, 1, nullptr, 0);
  hipLaunchKernelGGL(u_k, dim3(65536/256), blk, 0, stream, v_f, ba_hmat, u);
  hipLaunchKernelGGL(att_k, dim3(128), dim3(64), 0, stream, u, q_, ba_hbias, att);
  for (int g=0; g<2; g++){
    hipLaunchKernelGGL((mgemm_b<false>), dim3(64, 8), blk, 0, stream,
                       que_seq, 512L, bcqT_b + (long)g*512*512, bc_qb + (long)g*512, (void*)qg, 512, 4096, 512, 512, 1, nullptr, 0);
    hipLaunchKernelGGL((mgemm_b<false>), dim3(1, 8), blk, 0, stream,
                       evi_b, 512L, bcvT_b + (long)g*512*512, bc_vb + (long)g*512, (void*)vg, 512, 64, 512, 512, 1, nullptr, 0);
    hipLaunchKernelGGL(bi_k, dim3(64), dim3(512), 0, stream, att, vg, qg, bi_b, g);
    hipLaunchKernelGGL((mgemm_b<false>), dim3(1, 8), blk, 0, stream,
                       bi_b, 512L, prjT_b + (long)g*512*512, prj_b + (long)g*512, (void*)upd, 512, 64, 512, 512, 0, nullptr, 0);
    hipLaunchKernelGGL(addq_k, dim3((unsigned)((64L*64*512+255)/256)), blk, 0, stream, que_seq, upd);
  }
  hipLaunchKernelGGL(meanq_k, dim3(64), dim3(512), 0, stream, que_seq, fuse_qe);

  // ---- classifier ----
  hipLaunchKernelGGL(fuse_k, dim3((unsigned)((448L*4096+255)/256)), blk, 0, stream, que_vec, opt_feat, evi_feat, fuse_qe, fuse_b);
  hipLaunchKernelGGL((mgemm_b<false>), dim3(7, 8), blk, 0, stream,
                     fuse_b, 4096L, clsT_b, cls_b1, (void*)clsh, 512, 448, 512, 4096, 1, nullptr, 0);
  hipLaunchKernelGGL(cls_final_k, dim3(448), dim3(64), 0, stream, clsh, cls_w2, cls_b2, opt_ix, (float*)d_out);
  hipLaunchKernelGGL(count_k, dim3(1), dim3(64), 0, stream, opt_ix, (float*)d_out);
}

// Round 12
// 2797.819 us; speedup vs baseline: 8.3562x; 1.4127x over previous
//
#include <hip/hip_runtime.h>
#include <hip/hip_bf16.h>
#include <cmath>

#define NEG_ (-1000000000.0f)

// dims
#define V_ 30000
#define E_ 300
#define EP_ 320
#define H_ 512
#define B_ 64
#define S_ 50
#define LS_ 32
#define LO_ 16
#define A_ 7

// unified token layout: [que 64x64][cp 3200x32][opt 448x16]
#define TOK_ 113664
#define ROWS_ 3712
#define CPB_ 4096
#define OPTB_ 106496

typedef __attribute__((ext_vector_type(8))) short bh8;
typedef __attribute__((ext_vector_type(4))) float f4;

__device__ __forceinline__ float wred_sum(float v){
#pragma unroll
  for (int o=32;o>0;o>>=1) v += __shfl_xor(v,o);
  return v;
}
__device__ __forceinline__ float wred_max(float v){
#pragma unroll
  for (int o=32;o>0;o>>=1) v = fmaxf(v,__shfl_xor(v,o));
  return v;
}
__device__ __forceinline__ float sigf(float x){ return 1.f/(1.f+expf(-x)); }
__device__ __forceinline__ float entf(float p){ return -(p*log2f(p) + (1.f-p)*log2f(1.f-p)); }
__device__ __forceinline__ unsigned short f2b(float f){
  unsigned x = __float_as_uint(f);
  x = x + 0x7FFF + ((x>>16)&1);
  return (unsigned short)(x>>16);
}
__device__ __forceinline__ float b2f(unsigned short u){
  return __uint_as_float(((unsigned)u)<<16);
}

// ---------------- weight conversion ----------------
__global__ void cvt_gk_k(const float* __restrict__ in, unsigned short* __restrict__ out,
                         int G, int K, int Kp){
  long idx = (long)blockIdx.x*256 + threadIdx.x;
  if (idx >= (long)G*Kp) return;
  int k = (int)(idx % Kp); long g = idx / Kp;
  out[idx] = (k < K) ? f2b(in[g*K + k]) : 0;
}
__global__ void cvt_kg_k(const float* __restrict__ in, unsigned short* __restrict__ out,
                         int G, int K, int Kp){
  long idx = (long)blockIdx.x*256 + threadIdx.x;
  if (idx >= (long)G*Kp) return;
  int k = (int)(idx % Kp); long g = idx / Kp;
  out[idx] = (k < K) ? f2b(in[(long)k*G + g]) : 0;
}

// fused GRU weight: Wcat[2048][832]; rows: [wi_r|wh_r],[wi_z|wh_z],[wi_n|0],[0|wh_n]
__global__ void build_wcat_k(const float* __restrict__ wi, const float* __restrict__ wh,
                             const float* __restrict__ bi, const float* __restrict__ bh,
                             unsigned short* __restrict__ Wcat, float* __restrict__ bcat){
  long idx = (long)blockIdx.x*256 + threadIdx.x;
  if (idx < 2048L*832){
    int k = (int)(idx % 832); long g = idx / 832;
    float v = 0.f;
    if (g < 1024){
      if (k < 320){ if (k < E_) v = wi[g*E_ + k]; }
      else v = wh[g*512 + (k-320)];
    } else if (g < 1536){
      if (k < 320 && k < E_) v = wi[g*E_ + k];
    } else {
      if (k >= 320) v = wh[(g-512)*512 + (k-320)];
    }
    Wcat[idx] = f2b(v);
  }
  if (idx < 2048){
    int g = (int)idx;
    float v;
    if (g < 1024) v = bi[g] + bh[g];
    else if (g < 1536) v = bi[g];
    else v = bh[g-512];
    bcat[g] = v;
  }
}

__global__ void score_fold_k(const float* __restrict__ w1, const float* __restrict__ b1,
                             const float* __restrict__ w2, const float* __restrict__ b2,
                             float* scv, float* scc){
  int k = blockIdx.x*256+threadIdx.x;
  if (k < H_){ float s=0; for(int j=0;j<H_;j++) s += w1[(long)k*H_+j]*w2[j]; scv[k]=s; }
  if (blockIdx.x==0 && threadIdx.x==0){ float s=0; for(int j=0;j<H_;j++) s += b1[j]*w2[j]; *scc = s + b2[0]; }
}

// token gather + per-seq-row token base
__global__ void gather_init_k(const int* __restrict__ que, const int* __restrict__ cp,
                              const int* __restrict__ opt, int* __restrict__ tokg, int* __restrict__ hg0){
  int i = blockIdx.x*256+threadIdx.x;
  if (i < TOK_){
    int v;
    if (i < CPB_) v = que[i];
    else if (i < OPTB_) v = cp[i-CPB_];
    else v = opt[i-OPTB_];
    tokg[i] = v;
  }
  if (i < ROWS_){
    int t;
    if (i < 64) t = i*64;
    else if (i < 3264) t = CPB_ + (i-64)*32;
    else t = OPTB_ + (i-3264)*16;
    hg0[i] = t;
  }
}
__global__ void fill_from_k(float* p, const float* v, long n){
  long i = (long)blockIdx.x*256 + threadIdx.x; if (i<n) p[i]=v[0];
}

// ---------------- all-bf16 MFMA GEMM ----------------
// out[r,g] = bias[g] + sum_k A[r][k] * W[g][k];  Kd%32==0.
// 64x64 tile, 4 waves, 2x2 mfma_f32_16x16x32_bf16 frags.  LDS [64][40] bf16.
// C/D: col=lane&15, row=(lane>>4)*4+reg  [HW-verified r8/r9].
template<bool OUTB>
__global__ __launch_bounds__(256) void mgemm_b(
    const unsigned short* __restrict__ A, long lda,
    const unsigned short* __restrict__ Wm, const float* __restrict__ bias,
    void* __restrict__ out, int ldo,
    int R, int G, int Kd, int relu)
{
  __shared__ short As[64][40];
  __shared__ short Bs[64][40];
  int tid = threadIdx.x;
  int r0 = blockIdx.x*64, g0 = blockIdx.y*64;
  int srow = tid>>2, ks = (tid&3)*8;
  int lane = tid&63, w = tid>>6;
  int wm = (w>>1)*32, wn = (w&1)*32;
  int l15 = lane&15, lk = (lane>>4)*8;
  f4 acc[2][2] = {};
  const unsigned short* ap = nullptr;
  int rr = r0 + srow;
  if (rr < R) ap = A + (long)rr*lda;
  int gg = g0 + srow;
  const unsigned short* wp = (gg < G) ? (Wm + (long)gg*Kd) : nullptr;
  for (int k0 = 0; k0 < Kd; k0 += 32){
    bh8 va, vb;
#pragma unroll
    for (int q=0;q<8;q++){ va[q]=0; vb[q]=0; }
    if (ap) va = *(const bh8*)(ap + k0 + ks);
    if (wp) vb = *(const bh8*)(wp + k0 + ks);
    *(bh8*)&As[srow][ks] = va;
    *(bh8*)&Bs[srow][ks] = vb;
    __syncthreads();
    bh8 af[2], bw[2];
#pragma unroll
    for (int i=0;i<2;i++){
      af[i] = *(bh8*)&As[wm + i*16 + l15][lk];
      bw[i] = *(bh8*)&Bs[wn + i*16 + l15][lk];
    }
#pragma unroll
    for (int i=0;i<2;i++)
#pragma unroll
      for (int j=0;j<2;j++)
        acc[i][j] = __builtin_amdgcn_mfma_f32_16x16x32_bf16(af[i], bw[j], acc[i][j], 0,0,0);
    __syncthreads();
  }
#pragma unroll
  for (int i=0;i<2;i++)
#pragma unroll
    for (int j=0;j<2;j++)
#pragma unroll
      for (int q=0;q<4;q++){
        int r = r0 + wm + i*16 + (lane>>4)*4 + q;
        int g = g0 + wn + j*16 + l15;
        if (r < R && g < G){
          float v = acc[i][j][q] + (bias ? bias[g] : 0.f);
          if (relu) v = fmaxf(v, 0.f);
          long off = (long)r*ldo + g;
          if (OUTB) ((unsigned short*)out)[off] = f2b(v);
          else      ((float*)out)[off] = v;
        }
      }
}

// ---------------- fused GRU step GEMM: gpre[r] = [emb(tok)|h_prev] @ Wcat^T + bcat ----------------
__global__ __launch_bounds__(256) void mgemm_step(
    const unsigned short* __restrict__ emb_b,   // [30000][320]
    const unsigned short* __restrict__ seq,     // [TOK_][512]
    const unsigned short* __restrict__ Wcat,    // [2048][832]
    const float* __restrict__ bcat,
    const int* __restrict__ tokg, const int* __restrict__ hg0,
    int t, unsigned short* __restrict__ gpre, int R)
{
  __shared__ short As[64][40];
  __shared__ short Bs[64][40];
  int tid = threadIdx.x;
  int r0 = blockIdx.x*64, g0 = blockIdx.y*64;
  int srow = tid>>2, ks = (tid&3)*8;
  int lane = tid&63, w = tid>>6;
  int wm=(w>>1)*32, wn=(w&1)*32;
  int l15=lane&15, lk=(lane>>4)*8;
  f4 acc[2][2] = {};
  const unsigned short* ap1 = nullptr;
  const unsigned short* ap2 = nullptr;
  int rr = r0 + srow;
  if (rr < R){
    long tok = (long)hg0[rr] + t;
    ap1 = emb_b + (long)tokg[tok]*EP_;
    if (t > 0) ap2 = seq + (tok-1)*512;
  }
  const unsigned short* wp = Wcat + (long)(g0+srow)*832;
  for (int k0=0; k0<832; k0+=32){
    bh8 va, vb;
#pragma unroll
    for (int q=0;q<8;q++){ va[q]=0; vb[q]=0; }
    if (k0 < 320){ if (ap1) va = *(const bh8*)(ap1 + k0 + ks); }
    else         { if (ap2) va = *(const bh8*)(ap2 + (k0-320) + ks); }
    vb = *(const bh8*)(wp + k0 + ks);
    *(bh8*)&As[srow][ks] = va;
    *(bh8*)&Bs[srow][ks] = vb;
    __syncthreads();
    bh8 af[2], bw[2];
#pragma unroll
    for (int i=0;i<2;i++){
      af[i] = *(bh8*)&As[wm + i*16 + l15][lk];
      bw[i] = *(bh8*)&Bs[wn + i*16 + l15][lk];
    }
#pragma unroll
    for (int i=0;i<2;i++)
#pragma unroll
      for (int j=0;j<2;j++)
        acc[i][j] = __builtin_amdgcn_mfma_f32_16x16x32_bf16(af[i], bw[j], acc[i][j], 0,0,0);
    __syncthreads();
  }
#pragma unroll
  for (int i=0;i<2;i++)
#pragma unroll
    for (int j=0;j<2;j++)
#pragma unroll
      for (int q=0;q<4;q++){
        int r = r0 + wm + i*16 + (lane>>4)*4 + q;
        int g = g0 + wn + j*16 + l15;
        if (r < R){
          gpre[(long)r*2048 + g] = f2b(acc[i][j][q] + bcat[g]);
        }
      }
}

// ---------------- GRU gate from fused preact ----------------
__global__ void gru_gate_f(const unsigned short* __restrict__ gpre,
                           unsigned short* __restrict__ seq, int t, int Nact){
  long idx = (long)blockIdx.x*256 + threadIdx.x;
  if (idx >= (long)Nact*H_) return;
  int row = (int)(idx >> 9); int j = (int)(idx & 511);
  long tok;
  if (row < 64) tok = (long)row*64 + t;
  else if (row < 3264) tok = CPB_ + (long)(row-64)*32 + t;
  else tok = OPTB_ + (long)(row-3264)*16 + t;
  const unsigned short* gp = gpre + (long)row*2048;
  float a  = b2f(gp[j]);
  float bz = b2f(gp[512+j]);
  float xn = b2f(gp[1024+j]);
  float hn = b2f(gp[1536+j]);
  float r = sigf(a), z = sigf(bz);
  float nn = tanhf(xn + r*hn);
  float hp = (t==0) ? 0.f : b2f(seq[(tok-1)*512 + j]);
  seq[tok*512 + j] = f2b((1.f-z)*nn + z*hp);
}

// ---------------- fused attflat score ----------------
__global__ __launch_bounds__(256) void mscore_k(
    const unsigned short* __restrict__ A,
    const unsigned short* __restrict__ Wm,
    const float* __restrict__ b1, const float* __restrict__ w2,
    float* __restrict__ sOut, int R)
{
  __shared__ short As[64][40];
  __shared__ short Bs[64][40];
  __shared__ float rsum[64][33];
  int tid = threadIdx.x;
  int r0 = blockIdx.x*64, g0 = blockIdx.y*64;
  int srow = tid>>2, ks = (tid&3)*8;
  int lane = tid&63, w = tid>>6;
  int wm = (w>>1)*32, wn = (w&1)*32;
  int l15 = lane&15, lk = (lane>>4)*8;
  f4 acc[2][2] = {};
  const unsigned short* ap = nullptr;
  int rr = r0 + srow;
  if (rr < R) ap = A + (long)rr*512;
  const unsigned short* wp = Wm + (long)(g0+srow)*512;
  for (int k0 = 0; k0 < 512; k0 += 32){
    bh8 va, vb;
#pragma unroll
    for (int q=0;q<8;q++){ va[q]=0; vb[q]=0; }
    if (ap) va = *(const bh8*)(ap + k0 + ks);
    vb = *(const bh8*)(wp + k0 + ks);
    *(bh8*)&As[srow][ks] = va;
    *(bh8*)&Bs[srow][ks] = vb;
    __syncthreads();
    bh8 af[2], bw[2];
#pragma unroll
    for (int i=0;i<2;i++){
      af[i] = *(bh8*)&As[wm + i*16 + l15][lk];
      bw[i] = *(bh8*)&Bs[wn + i*16 + l15][lk];
    }
#pragma unroll
    for (int i=0;i<2;i++)
#pragma unroll
      for (int j=0;j<2;j++)
        acc[i][j] = __builtin_amdgcn_mfma_f32_16x16x32_bf16(af[i], bw[j], acc[i][j], 0,0,0);
    __syncthreads();
  }
  int cont = (w&1)*16 + l15;
#pragma unroll
  for (int i=0;i<2;i++)
#pragma unroll
    for (int q=0;q<4;q++){
      float pr = 0.f;
#pragma unroll
      for (int j=0;j<2;j++){
        int g = g0 + wn + j*16 + l15;
        float y = fmaxf(acc[i][j][q] + b1[g], 0.f);
        pr += y * w2[g];
      }
      rsum[wm + i*16 + (lane>>4)*4 + q][cont] = pr;
    }
  __syncthreads();
  if (tid < 64){
    float ssum = 0.f;
#pragma unroll
    for (int c=0;c<32;c++) ssum += rsum[tid][c];
    if (r0+tid < R) atomicAdd(&sOut[r0+tid], ssum);
  }
}

// ---------------- unified attflat softmax + weighted sum ----------------
__global__ void flat_soft_u(const float* __restrict__ s,
                            const int* __restrict__ que_ix, const int* __restrict__ cp_ix,
                            const int* __restrict__ opt_ix,
                            const unsigned short* __restrict__ seq, unsigned short* __restrict__ pre){
  int n = blockIdx.x; int tid = threadIdx.x;
  int T; long tokbase; const int* ixp;
  if (n < 64){ T=64; tokbase=(long)n*64; ixp = que_ix + (long)n*64; }
  else if (n < 3264){ int br=n-64; T=32; tokbase=CPB_+(long)br*32; ixp = cp_ix + (long)br*32; }
  else { int br=n-3264; T=16; tokbase=OPTB_+(long)br*16; ixp = opt_ix + (long)br*16; }
  __shared__ float aw[64];
  if (tid < 64){
    float val = -INFINITY;
    if (tid < T) val = (ixp[tid]==0) ? NEG_ : s[tokbase+tid];
    float mx = wred_max(val);
    float e = (tid < T) ? expf(val-mx) : 0.f;
    float ssum = wred_sum(e);
    if (tid < T) aw[tid] = e/ssum;
  }
  __syncthreads();
  for (int h=tid; h<512; h+=256){
    float acc=0;
    for (int t=0;t<T;t++) acc += aw[t]*b2f(seq[(tokbase+t)*512+h]);
    pre[(long)n*512+h] = f2b(acc);
  }
}

// ---------------- span scores ----------------
__global__ void sent_empty_k(const int* __restrict__ cp_ix, int* __restrict__ se){
  int i = blockIdx.x*256+threadIdx.x;
  if (i < B_*S_){ const int* p = cp_ix + (long)i*LS_; int e=1; for(int t=0;t<LS_;t++) if(p[t]!=0){e=0;break;} se[i]=e; }
}
__global__ void qdot_k(const float* __restrict__ que_vec, const float* __restrict__ scv, float* qdot){
  int b = blockIdx.x; int d = threadIdx.x;  // 128
  const float* qv = que_vec + (long)b*512;
  float m = 0.25f*(qv[4*d]+qv[4*d+1]+qv[4*d+2]+qv[4*d+3]);
  float v = m*scv[d];
  __shared__ float sred[2];
  float w = wred_sum(v);
  if ((threadIdx.x&63)==0) sred[threadIdx.x>>6] = w;
  __syncthreads();
  if (threadIdx.x==0) qdot[b] = sred[0]+sred[1];
}
__global__ void que_ent_k(const float* __restrict__ que_vec, const float* __restrict__ scv,
                          const float* __restrict__ scc, float* que_ent){
  int b = blockIdx.x; int lane = threadIdx.x;  // 64
  float acc=0; for(int d=lane;d<512;d+=64) acc += que_vec[(long)b*512+d]*scv[d];
  acc = wred_sum(acc);
  if (lane==0){ float p = sigf(acc + scc[0]); que_ent[b] = entf(p); }
}
__global__ void ce_k(const float* __restrict__ cp_feat,
                     const float* __restrict__ qdot, const float* __restrict__ scv,
                     const float* __restrict__ scc, float* __restrict__ ce){
  int bj = blockIdx.x;  // 64*150
  int b = bj/150, j = bj%150;
  int sI = j/3, wi = j%3;
  int lane = threadIdx.x;  // 64
  float dsp = 0.f;
  for (int e=lane; e<1536; e+=64){
    int off = e >> 9; int dd = e & 511;
    if (off <= wi && sI+off < S_)
      dsp += cp_feat[((long)(b*S_ + sI+off))*512 + dd] * scv[e/3];
  }
  float dqe = 0.f;
  for (int d=128+lane; d<512; d+=64){
    int e0 = 4*d - 512;
    int off = e0 >> 9; int dd = e0 & 511;
    float m = 0.f;
    if (off <= wi && sI+off < S_){
      const float* cf = cp_feat + ((long)(b*S_ + sI+off))*512 + dd;
      m = 0.25f*(cf[0]+cf[1]+cf[2]+cf[3]);
    }
    dqe += m*scv[d];
  }
  dsp = wred_sum(dsp)*(1.f/3.f); dqe = wred_sum(dqe);
  if (lane==0){
    float evi = sigf(dsp + scc[0]);
    float pq  = sigf(dqe + qdot[b] + scc[0]);
    ce[bj] = evi * entf(pq);
  }
}
__global__ void argmax_k(const float* __restrict__ ce, const float* __restrict__ que_ent,
                         const int* __restrict__ sent_e, const float* __restrict__ cp_feat,
                         float* __restrict__ evi_feat, unsigned short* __restrict__ evi_b){
  int b = blockIdx.x;
  __shared__ int bix;
  if (threadIdx.x==0){
    float best = -INFINITY; int bidx = 0;
    for (int j=0;j<150;j++){
      float v = sent_e[b*S_ + j/3] ? NEG_ : (que_ent[b] - ce[b*150+j]);
      if (v > best){ best = v; bidx = j; }
    }
    bix = bidx;
  }
  __syncthreads();
  int sI = bix/3, wi = bix%3;
  for (int d=threadIdx.x; d<512; d+=blockDim.x){
    float sum = 0.f;
#pragma unroll
    for (int q=0;q<3;q++){
      int e = 3*d + q; int off = e >> 9; int dd = e & 511;
      if (off <= wi && sI+off < S_) sum += cp_feat[((long)(b*S_ + sI+off))*512 + dd];
    }
    float v = sum * (1.f/3.f);
    evi_feat[(long)b*512+d] = v;
    evi_b[(long)b*512+d] = f2b(v);
  }
}

// ---------------- bilinear attention ----------------
__global__ void u_k(const float* __restrict__ v_f, const float* __restrict__ hmat, float* __restrict__ u){
  int idx = blockIdx.x*256+threadIdx.x;
  if (idx >= 65536) return;
  int k = idx & 511; int g = (idx >> 9) & 1; int b = idx >> 10;
  u[idx] = v_f[(long)b*512+k]*hmat[(long)g*512+k];
}
__global__ void att_k(const float* __restrict__ u, const float* __restrict__ q_,
                      const float* __restrict__ hbias, float* __restrict__ att){
  int bg = blockIdx.x;  // 128
  int b = bg >> 1, g = bg & 1;
  int lane = threadIdx.x;  // 64
  const float* up = u + (long)bg*512;
  const float* qp = q_ + ((long)b*64 + lane)*512;
  float dot = 0;
  for (int k=0;k<512;k++) dot += up[k]*qp[k];
  dot += hbias[g];
  float mx = wred_max(dot);
  float e = expf(dot - mx);
  float ssum = wred_sum(e);
  att[(long)bg*64 + lane] = e/ssum;
}
__global__ void bi_k(const float* __restrict__ att, const float* __restrict__ vg,
                     const float* __restrict__ qg, unsigned short* __restrict__ bi, int g){
  int b = blockIdx.x; int k = threadIdx.x;  // 512
  __shared__ float a[64];
  if (k < 64) a[k] = att[((long)b*2+g)*64 + k];
  __syncthreads();
  float acc = 0;
  for (int q=0;q<64;q++) acc += a[q]*qg[((long)b*64+q)*512 + k];
  bi[(long)b*512+k] = f2b(vg[(long)b*512+k]*acc);
}
__global__ void addq_k(unsigned short* __restrict__ q, const float* __restrict__ upd){
  long idx = (long)blockIdx.x*256 + threadIdx.x;  // 64*64*512
  if (idx >= 64L*64*512) return;
  int h = (int)(idx & 511); int b = (int)(idx >> 15);
  q[idx] = f2b(b2f(q[idx]) + upd[(long)b*512 + h]);
}
__global__ void meanq_k(const unsigned short* __restrict__ q, float* __restrict__ fq){
  int b = blockIdx.x; int h = threadIdx.x;  // 512
  float acc=0; for(int t=0;t<64;t++) acc += b2f(q[((long)b*64+t)*512+h]);
  fq[(long)b*512+h] = acc*(1.f/64.f);
}

// ---------------- classifier ----------------
__global__ void fuse_k(const float* __restrict__ que_vec, const float* __restrict__ opt_feat,
                       const float* __restrict__ evi_feat, const float* __restrict__ fuse_qe,
                       unsigned short* __restrict__ fuse){
  long idx = (long)blockIdx.x*256+threadIdx.x;  // 448*4096
  if (idx >= 448L*4096) return;
  int e = (int)(idx & 4095); long r = idx >> 12;
  int c = e >> 9, d = e & 511;
  int b = (int)(r / 7);
  float qv = que_vec[(long)b*512+d], ov = opt_feat[r*512+d], ev = evi_feat[(long)b*512+d], fq = fuse_qe[(long)b*512+d];
  float val;
  switch(c){
    case 0: val=qv; break; case 1: val=ov; break; case 2: val=ev; break;
    case 3: val=qv*ev; break; case 4: val=ev*ov; break; case 5: val=qv*ov; break;
    case 6: val=fq; break; default: val=qv*ov*fq; break;
  }
  fuse[idx]=f2b(val);
}
__global__ void cls_final_k(const float* __restrict__ clsh, const float* __restrict__ cls_w2,
                            const float* __restrict__ cls_b2, const int* __restrict__ opt_ix,
                            float* __restrict__ outp){
  int r = blockIdx.x;  // 448
  int lane = threadIdx.x;  // 64
  float acc=0;
  for (int j=lane;j<512;j+=64) acc += clsh[(long)r*512+j]*cls_w2[j];
  acc = wred_sum(acc);
  if (lane==0){
    bool empty = true;
    for (int t=0;t<LO_;t++) if (opt_ix[(long)r*LO_+t]!=0) { empty=false; break; }
    outp[r] = empty ? NEG_ : (acc + cls_b2[0]);
  }
}
__global__ void count_k(const int* __restrict__ opt_ix, float* __restrict__ outp){
  int b = threadIdx.x;  // 64
  if (b < B_){
    int c=0;
    for(int a=0;a<A_;a++){
      bool e=true;
      for(int t=0;t<LO_;t++) if(opt_ix[((long)b*A_+a)*LO_+t]!=0){e=false;break;}
      if (!e) c++;
    }
    outp[448+b]=(float)c;
  }
}

// ---------------- host orchestration ----------------
extern "C" void kernel_launch(void* const* d_in, const int* in_sizes, int n_in,
                              void* d_out, int out_size, void* d_ws, size_t ws_size,
                              hipStream_t stream) {
  const int*   que_ix  = (const int*)d_in[0];
  const int*   opt_ix  = (const int*)d_in[1];
  const int*   cp_ix   = (const int*)d_in[2];
  const float* emb     = (const float*)d_in[3];
  const float* gru_wi  = (const float*)d_in[4];
  const float* gru_wh  = (const float*)d_in[5];
  const float* gru_bi  = (const float*)d_in[6];
  const float* gru_bh  = (const float*)d_in[7];
  const float* flat_w1 = (const float*)d_in[8];
  const float* flat_b1 = (const float*)d_in[9];
  const float* flat_w2 = (const float*)d_in[10];
  const float* flat_b2 = (const float*)d_in[11];
  const float* flat_mw = (const float*)d_in[12];
  const float* flat_mb = (const float*)d_in[13];
  const float* score_w1= (const float*)d_in[14];
  const float* score_b1= (const float*)d_in[15];
  const float* score_w2= (const float*)d_in[16];
  const float* score_b2= (const float*)d_in[17];
  const float* ba_vw   = (const float*)d_in[18];
  const float* ba_vb   = (const float*)d_in[19];
  const float* ba_qw   = (const float*)d_in[20];
  const float* ba_qb   = (const float*)d_in[21];
  const float* ba_hmat = (const float*)d_in[22];
  const float* ba_hbias= (const float*)d_in[23];
  const float* bc_vw   = (const float*)d_in[24];
  const float* bc_vb   = (const float*)d_in[25];
  const float* bc_qw   = (const float*)d_in[26];
  const float* bc_qb   = (const float*)d_in[27];
  const float* prj_w   = (const float*)d_in[28];
  const float* prj_b   = (const float*)d_in[29];
  const float* cls_w1  = (const float*)d_in[30];
  const float* cls_b1  = (const float*)d_in[31];
  const float* cls_w2  = (const float*)d_in[32];
  const float* cls_b2  = (const float*)d_in[33];

  float* Wp = (float*)d_ws;
  size_t o = 0;
  auto F  = [&](size_t n){ o = (o+3)&~(size_t)3; float* p = Wp + o; o += n; return p; };
  auto FS = [&](size_t nsh){ return (unsigned short*)F((nsh+1)/2); };

  unsigned short* seq   = FS((size_t)TOK_*512);     // 116 MB
  unsigned short* gpre  = FS((size_t)ROWS_*2048);   // 15 MB
  unsigned short* emb_b = FS(30000L*EP_);           // 19 MB
  unsigned short* Wcat  = FS(2048L*832);
  float*          bcat  = F(2048);
  unsigned short* w1T_b = FS(512L*512);
  unsigned short* mwT_b = FS(512L*512);
  unsigned short* vwT_b = FS(512L*512);
  unsigned short* qwT_b = FS(512L*512);
  unsigned short* bcvT_b= FS(2L*512*512);
  unsigned short* bcqT_b= FS(2L*512*512);
  unsigned short* prjT_b= FS(2L*512*512);
  unsigned short* clsT_b= FS(512L*4096);
  int*   tokg    = (int*)F(TOK_);
  int*   hg0     = (int*)F(ROWS_);
  float* scv     = F(512);
  float* scc     = F(8);
  float* sbuf    = F(TOK_);
  unsigned short* pre_b = FS((size_t)ROWS_*512);
  float* feats   = F((size_t)ROWS_*512);
  float* qdot    = F(64);
  float* que_ent = F(64);
  float* ce      = F(9600);
  int*   sent_e  = (int*)F(3200);
  float* evi_feat= F(64L*512);
  unsigned short* evi_b = FS(64L*512);
  float* q_      = F(4096L*512);
  float* u       = F(128L*512);
  float* att     = F(128L*64);
  float* v_f     = F(64L*512);
  float* vg      = F(64L*512);
  float* qg      = F(4096L*512);
  unsigned short* bi_b = FS(64L*512);
  float* upd     = F(64L*512);
  float* fuse_qe = F(64L*512);
  unsigned short* fuse_b = FS(448L*4096);
  float* clsh    = F(448L*512);

  float* que_vec  = feats;                 // rows 0..63
  float* cp_feat  = feats + 64L*512;       // rows 64..3263
  float* opt_feat = feats + 3264L*512;     // rows 3264..3711

  dim3 blk(256);
  auto CVT = [&](const float* in, unsigned short* out, int G, int K, int Kp, bool kg){
    long n = (long)G*Kp;
    if (kg) hipLaunchKernelGGL(cvt_kg_k, dim3((unsigned)((n+255)/256)), blk, 0, stream, in, out, G, K, Kp);
    else    hipLaunchKernelGGL(cvt_gk_k, dim3((unsigned)((n+255)/256)), blk, 0, stream, in, out, G, K, Kp);
  };
  CVT(emb,     emb_b, 30000, E_, EP_, false);
  CVT(flat_w1, w1T_b, 512, 512, 512, true);
  CVT(flat_mw, mwT_b, 512, 512, 512, true);
  CVT(ba_vw,   vwT_b, 512, 512, 512, true);
  CVT(ba_qw,   qwT_b, 512, 512, 512, true);
  for (int g=0; g<2; g++){
    CVT(bc_vw + (long)g*512*512, bcvT_b + (long)g*512*512, 512, 512, 512, true);
    CVT(bc_qw + (long)g*512*512, bcqT_b + (long)g*512*512, 512, 512, 512, true);
    CVT(prj_w + (long)g*512*512, prjT_b + (long)g*512*512, 512, 512, 512, true);
  }
  CVT(cls_w1, clsT_b, 512, 4096, 4096, true);
  hipLaunchKernelGGL(build_wcat_k, dim3((unsigned)((2048L*832+255)/256)), blk, 0, stream,
                     gru_wi, gru_wh, gru_bi, gru_bh, Wcat, bcat);
  hipLaunchKernelGGL(score_fold_k, dim3(2), blk, 0, stream, score_w1, score_b1, score_w2, score_b2, scv, scc);
  hipLaunchKernelGGL(gather_init_k, dim3((TOK_+255)/256), blk, 0, stream, que_ix, cp_ix, opt_ix, tokg, hg0);

  // ---- unified 64-step GRU loop (fused preactivation GEMM + gate) ----
  for (int t=0; t<64; t++){
    int Nact = (t<16) ? 3712 : ((t<32) ? 3264 : 64);
    hipLaunchKernelGGL(mgemm_step, dim3((unsigned)((Nact+63)/64), 32), blk, 0, stream,
                       emb_b, seq, Wcat, bcat, tokg, hg0, t, gpre, Nact);
    long tot = (long)Nact*512;
    hipLaunchKernelGGL(gru_gate_f, dim3((unsigned)((tot+255)/256)), blk, 0, stream, gpre, seq, t, Nact);
  }

  // ---- batched attflat over all branches ----
  hipLaunchKernelGGL(fill_from_k, dim3((TOK_+255)/256), blk, 0, stream, sbuf, flat_b2, (long)TOK_);
  hipLaunchKernelGGL(mscore_k, dim3((TOK_+63)/64, 8), blk, 0, stream, seq, w1T_b, flat_b1, flat_w2, sbuf, TOK_);
  hipLaunchKernelGGL(flat_soft_u, dim3(ROWS_), blk, 0, stream, sbuf, que_ix, cp_ix, opt_ix, seq, pre_b);
  hipLaunchKernelGGL((mgemm_b<false>), dim3((ROWS_+63)/64, 8), blk, 0, stream,
                     pre_b, 512L, mwT_b, flat_mb, (void*)feats, 512, ROWS_, 512, 512, 0);

  // ---- span scores + info gain + evidence ----
  hipLaunchKernelGGL(sent_empty_k, dim3((B_*S_+255)/256), blk, 0, stream, cp_ix, sent_e);
  hipLaunchKernelGGL(qdot_k, dim3(64), dim3(128), 0, stream, que_vec, scv, qdot);
  hipLaunchKernelGGL(que_ent_k, dim3(64), dim3(64), 0, stream, que_vec, scv, scc, que_ent);
  hipLaunchKernelGGL(ce_k, dim3(64*150), dim3(64), 0, stream, cp_feat, qdot, scv, scc, ce);
  hipLaunchKernelGGL(argmax_k, dim3(64), dim3(256), 0, stream, ce, que_ent, sent_e, cp_feat, evi_feat, evi_b);

  // ---- bilinear attention fusion (que tokens = seq[0..4096)) ----
  hipLaunchKernelGGL((mgemm_b<false>), dim3(1, 8), blk, 0, stream,
                     evi_b, 512L, vwT_b, ba_vb, (void*)v_f, 512, 64, 512, 512, 1);
  hipLaunchKernelGGL((mgemm_b<false>), dim3(64, 8), blk, 0, stream,
                     seq, 512L, qwT_b, ba_qb, (void*)q_, 512, 4096, 512, 512, 1);
  hipLaunchKernelGGL(u_k, dim3(65536/256), blk, 0, stream, v_f, ba_hmat, u);
  hipLaunchKernelGGL(att_k, dim3(128), dim3(64), 0, stream, u, q_, ba_hbias, att);
  for (int g=0; g<2; g++){
    hipLaunchKernelGGL((mgemm_b<false>), dim3(64, 8), blk, 0, stream,
                       seq, 512L, bcqT_b + (long)g*512*512, bc_qb + (long)g*512, (void*)qg, 512, 4096, 512, 512, 1);
    hipLaunchKernelGGL((mgemm_b<false>), dim3(1, 8), blk, 0, stream,
                       evi_b, 512L, bcvT_b + (long)g*512*512, bc_vb + (long)g*512, (void*)vg, 512, 64, 512, 512, 1);
    hipLaunchKernelGGL(bi_k, dim3(64), dim3(512), 0, stream, att, vg, qg, bi_b, g);
    hipLaunchKernelGGL((mgemm_b<false>), dim3(1, 8), blk, 0, stream,
                       bi_b, 512L, prjT_b + (long)g*512*512, prj_b + (long)g*512, (void*)upd, 512, 64, 512, 512, 0);
    hipLaunchKernelGGL(addq_k, dim3((unsigned)((64L*64*512+255)/256)), blk, 0, stream, seq, upd);
  }
  hipLaunchKernelGGL(meanq_k, dim3(64), dim3(512), 0, stream, seq, fuse_qe);

  // ---- classifier ----
  hipLaunchKernelGGL(fuse_k, dim3((unsigned)((448L*4096+255)/256)), blk, 0, stream, que_vec, opt_feat, evi_feat, fuse_qe, fuse_b);
  hipLaunchKernelGGL((mgemm_b<false>), dim3(7, 8), blk, 0, stream,
                     fuse_b, 4096L, clsT_b, cls_b1, (void*)clsh, 512, 448, 512, 4096, 1);
  hipLaunchKernelGGL(cls_final_k, dim3(448), dim3(64), 0, stream, clsh, cls_w2, cls_b2, opt_ix, (float*)d_out);
  hipLaunchKernelGGL(count_k, dim3(1), dim3(64), 0, stream, opt_ix, (float*)d_out);
}